// Round 14
// baseline (438.740 us; speedup 1.0000x reference)
//
#include <hip/hip_runtime.h>

// BasisAttention: B=16,S=2048,D=1024,N=4096,K_TOP=64. fp32 in/out.
// R4: approx-then-rescore. R5: scores = Xn@(Km Wq)^T. R8: weight-chain fusion.
// R9/R11: XCD swizzle + L2-fit co-residency. R10: int8 approx pass.
// R11: indirect rescore staging, merged final_k.
// R12 refuted 64KB-LDS cap; R13 confirmed REGISTER cap (acc AGPRs):
//     64-AGPR waves -> 2 blocks/CU, MfmaUtil 36->41.5.
// R14: scores1 -> 256-thread/4-wave blocks, 128x128 tile, per-wave 64x64,
//     ~124 regs + launch_bounds(256,4) + LDS 32.5KB -> 4 independent
//     blocks/CU (loose barrier coupling, m114 TLP overlap). Grid 8192.

namespace {

constexpr int D_DIM = 1024;
constexpr int NE    = 4096;
constexpr int BATCH = 16;
constexpr int SEQ   = 2048;
constexpr int MX    = BATCH * SEQ;   // 32768
constexpr int KTOP  = 64;
constexpr int CAND  = 128;           // candidates per batch
constexpr int BK    = 32;

using f32x4  = __attribute__((ext_vector_type(4))) float;
using bf16x8 = __attribute__((ext_vector_type(8))) short;
using i32x4  = __attribute__((ext_vector_type(4))) int;

__device__ inline unsigned encf(float f) {
  unsigned u = __float_as_uint(f);
  return (u & 0x80000000u) ? ~u : (u | 0x80000000u);
}
__device__ inline float decf(unsigned e) {
  unsigned u = (e & 0x80000000u) ? (e ^ 0x80000000u) : ~e;
  return __uint_as_float(u);
}

__device__ inline unsigned short f2bf(float f) {  // RNE float->bf16 bits
  unsigned u = __float_as_uint(f);
  unsigned lsb = (u >> 16) & 1u;
  u += 0x7fffu + lsb;
  return (unsigned short)(u >> 16);
}
__device__ inline float bf2f(unsigned short h) {
  return __uint_as_float(((unsigned)h) << 16);
}

__device__ inline void gload16(const void* gsrc, void* ldst) {
  __builtin_amdgcn_global_load_lds(
      (const __attribute__((address_space(1))) unsigned int*)gsrc,
      (__attribute__((address_space(3))) unsigned int*)ldst, 16, 0, 0);
}

#define LGK0_SB() do { asm volatile("s_waitcnt lgkmcnt(0)" ::: "memory"); \
                       __builtin_amdgcn_sched_barrier(0); } while (0)

// ---------------- K1: per-row rsqrt(mean(x^2)+eps) ----------------
__global__ void row_rinv_k(const float* __restrict__ X, float* __restrict__ rinv) {
  __shared__ float l4[4];
  int row = blockIdx.x;
  float4 v = ((const float4*)(X + (size_t)row * D_DIM))[threadIdx.x];
  float ss = v.x * v.x + v.y * v.y + v.z * v.z + v.w * v.w;
  for (int o = 32; o > 0; o >>= 1) ss += __shfl_xor(ss, o);
  int lane = threadIdx.x & 63, w = threadIdx.x >> 6;
  if (lane == 0) l4[w] = ss;
  __syncthreads();
  if (threadIdx.x == 0) {
    float t = l4[0] + l4[1] + l4[2] + l4[3];
    rinv[row] = rsqrtf(t * (1.0f / D_DIM) + 1e-6f);
  }
}

// ---------------- K1a: fused per-row rinv + int8 quant of X ----------------
__global__ void rinv_quantx_k(const float* __restrict__ X, float* __restrict__ rinv,
                              float* __restrict__ sxr, int* __restrict__ XQ) {
  __shared__ float l4[4], m4[4];
  int row = blockIdx.x;
  float4 v = ((const float4*)(X + (size_t)row * D_DIM))[threadIdx.x];
  float ss = v.x * v.x + v.y * v.y + v.z * v.z + v.w * v.w;
  float am = fmaxf(fmaxf(fabsf(v.x), fabsf(v.y)), fmaxf(fabsf(v.z), fabsf(v.w)));
  for (int o = 32; o > 0; o >>= 1) {
    ss += __shfl_xor(ss, o);
    am = fmaxf(am, __shfl_xor(am, o));
  }
  int lane = threadIdx.x & 63, w = threadIdx.x >> 6;
  if (lane == 0) { l4[w] = ss; m4[w] = am; }
  __syncthreads();
  float t  = l4[0] + l4[1] + l4[2] + l4[3];
  float amax = fmaxf(fmaxf(m4[0], m4[1]), fmaxf(m4[2], m4[3]));
  amax = fmaxf(amax, 1e-30f);
  float ri = rsqrtf(t * (1.0f / D_DIM) + 1e-6f);
  if (threadIdx.x == 0) {
    rinv[row] = ri;
    sxr[row]  = ri * amax * (1.0f / 127.0f);
  }
  float qs = 127.0f / amax;
  int q0 = (int)rintf(v.x * qs) & 0xff;
  int q1 = (int)rintf(v.y * qs) & 0xff;
  int q2 = (int)rintf(v.z * qs) & 0xff;
  int q3 = (int)rintf(v.w * qs) & 0xff;
  XQ[(size_t)row * 256 + threadIdx.x] = q0 | (q1 << 8) | (q2 << 16) | (q3 << 24);
}

// ---------------- K1e: int8 quant of P rows (from bf16 hi/lo) ----------------
__global__ void quant_p_k(const unsigned short* __restrict__ PH,
                          const unsigned short* __restrict__ PL,
                          float* __restrict__ sp, int* __restrict__ PQ) {
  __shared__ float m4[4];
  int row = blockIdx.x;
  ushort4 h = *(const ushort4*)(PH + (size_t)row * D_DIM + threadIdx.x * 4);
  ushort4 l = *(const ushort4*)(PL + (size_t)row * D_DIM + threadIdx.x * 4);
  float p0 = bf2f(h.x) + bf2f(l.x);
  float p1 = bf2f(h.y) + bf2f(l.y);
  float p2 = bf2f(h.z) + bf2f(l.z);
  float p3 = bf2f(h.w) + bf2f(l.w);
  float am = fmaxf(fmaxf(fabsf(p0), fabsf(p1)), fmaxf(fabsf(p2), fabsf(p3)));
  for (int o = 32; o > 0; o >>= 1) am = fmaxf(am, __shfl_xor(am, o));
  int lane = threadIdx.x & 63, w = threadIdx.x >> 6;
  if (lane == 0) m4[w] = am;
  __syncthreads();
  float amax = fmaxf(fmaxf(m4[0], m4[1]), fmaxf(m4[2], m4[3]));
  amax = fmaxf(amax, 1e-30f);
  if (threadIdx.x == 0) sp[row] = amax * (1.0f / 127.0f);
  float qs = 127.0f / amax;
  int q0 = (int)rintf(p0 * qs) & 0xff;
  int q1 = (int)rintf(p1 * qs) & 0xff;
  int q2 = (int)rintf(p2 * qs) & 0xff;
  int q3 = (int)rintf(p3 * qs) & 0xff;
  PQ[(size_t)row * 256 + threadIdx.x] = q0 | (q1 << 8) | (q2 << 16) | (q3 << 24);
}

// ---------------- K1b: fused Wq fp32-transpose + Wk scaled bf16-split-transpose ----------------
__global__ void prep_w_k(const float* __restrict__ Wq, const float* __restrict__ Wk,
                         const float* __restrict__ cw, float* __restrict__ T,
                         unsigned short* __restrict__ H, unsigned short* __restrict__ L) {
  __shared__ float t[32][33], u[32][33];
  int k0 = blockIdx.x * 32, d0 = blockIdx.y * 32;
  int tx = threadIdx.x & 31, ty4 = (threadIdx.x >> 5) * 4;
#pragma unroll
  for (int i = 0; i < 4; ++i) {
    t[ty4 + i][tx] = Wq[(size_t)(d0 + ty4 + i) * D_DIM + k0 + tx];
    u[ty4 + i][tx] = Wk[(size_t)(d0 + ty4 + i) * D_DIM + k0 + tx];
  }
  __syncthreads();
#pragma unroll
  for (int i = 0; i < 4; ++i) {
    int a = ty4 + i;
    T[(size_t)(k0 + a) * D_DIM + d0 + tx] = t[tx][a];
    float v = u[tx][a] * cw[k0 + a];
    unsigned short h = f2bf(v);
    H[(size_t)(k0 + a) * D_DIM + d0 + tx] = h;
    L[(size_t)(k0 + a) * D_DIM + d0 + tx] = f2bf(v - bf2f(h));
  }
}

// ---------------- K2: O = rowscale(A_f32) @ B(hi,lo)^T (3-product) ----------------
template <int FPOUT>
__global__ __launch_bounds__(256, 2) void gemm_a32_k(
    const float* __restrict__ A, const float* __restrict__ rinv,
    const unsigned short* __restrict__ BH, const unsigned short* __restrict__ BL,
    unsigned short* __restrict__ OH, unsigned short* __restrict__ OL,
    float* __restrict__ Of) {
  __shared__ __align__(16) float lA[128 * 32];
  __shared__ __align__(16) unsigned short lBH[128 * 32];
  __shared__ __align__(16) unsigned short lBL[128 * 32];
  __shared__ float ldsR[128];

  int tid = threadIdx.x;
  int lane = tid & 63, wid = tid >> 6;
  int wr = wid >> 1, wc = wid & 1;
  int fr = lane & 15, fg = lane >> 4;
  long m0 = (long)blockIdx.x * 128;
  long n0 = (long)blockIdx.y * 128;

  if (tid < 128) ldsR[tid] = rinv ? rinv[m0 + tid] : 1.0f;

  f32x4 acc[4][4] = {};

  for (int kk = 0; kk < D_DIM; kk += BK) {
#pragma unroll
    for (int i = 0; i < 4; ++i) {
      int chunk = i * 256 + tid;
      int r = chunk >> 3, c = chunk & 7;
      int cs = c ^ (r & 7);
      const float* src = A + (m0 + r) * (long)D_DIM + kk + cs * 4;
      gload16(src, (void*)(lA + ((i * 256 + (tid & ~63)) << 2)));
    }
#pragma unroll
    for (int i = 0; i < 2; ++i) {
      int chunk = i * 256 + tid;
      int r = chunk >> 2, c = chunk & 3;
      int cs = c ^ ((r >> 1) & 3);
      long boff = (n0 + r) * (long)D_DIM + kk + cs * 8;
      int lo = (i * 256 + (tid & ~63)) << 3;
      gload16(BH + boff, (void*)(lBH + lo));
      gload16(BL + boff, (void*)(lBL + lo));
    }
    __syncthreads();

    bf16x8 aH[4], aL[4], bH[4], bL[4];
#pragma unroll
    for (int m = 0; m < 4; ++m) {
      int row = wr * 64 + m * 16 + fr;
      int rm = row & 7;
      f32x4 p0 = *(const f32x4*)(lA + row * 32 + (((fg * 2 + 0) ^ rm) * 4));
      f32x4 p1 = *(const f32x4*)(lA + row * 32 + (((fg * 2 + 1) ^ rm) * 4));
#pragma unroll
      for (int e = 0; e < 8; ++e) {
        float f = (e < 4) ? p0[e] : p1[e - 4];
        unsigned short h = f2bf(f);
        aH[m][e] = (short)h;
        aL[m][e] = (short)f2bf(f - bf2f(h));
      }
    }
#pragma unroll
    for (int n = 0; n < 4; ++n) {
      int row = wc * 64 + n * 16 + fr;
      int sc = fg ^ ((row >> 1) & 3);
      bH[n] = *(const bf16x8*)(lBH + row * 32 + sc * 8);
      bL[n] = *(const bf16x8*)(lBL + row * 32 + sc * 8);
    }
#pragma unroll
    for (int m = 0; m < 4; ++m)
#pragma unroll
      for (int n = 0; n < 4; ++n) {
        acc[m][n] = __builtin_amdgcn_mfma_f32_16x16x32_bf16(aH[m], bH[n], acc[m][n], 0, 0, 0);
        acc[m][n] = __builtin_amdgcn_mfma_f32_16x16x32_bf16(aH[m], bL[n], acc[m][n], 0, 0, 0);
        acc[m][n] = __builtin_amdgcn_mfma_f32_16x16x32_bf16(aL[m], bH[n], acc[m][n], 0, 0, 0);
      }
    __syncthreads();
  }

#pragma unroll
  for (int m = 0; m < 4; ++m) {
#pragma unroll
    for (int j = 0; j < 4; ++j) {
      int rloc = wr * 64 + m * 16 + fg * 4 + j;
      float rv = ldsR[rloc];
      long grow = m0 + rloc;
#pragma unroll
      for (int n = 0; n < 4; ++n) {
        long gcol = n0 + wc * 64 + n * 16 + fr;
        float v = acc[m][n][j] * rv;
        if (FPOUT) {
          Of[grow * D_DIM + gcol] = v;
        } else {
          unsigned short h = f2bf(v);
          OH[grow * D_DIM + gcol] = h;
          OL[grow * D_DIM + gcol] = f2bf(v - bf2f(h));
        }
      }
    }
  }
}

// ---------------- K3a: APPROX scores INT8 — 128x128 tile, 4 waves (2m x 2n),
// per-wave 64x64 (acc[4][4]=64 AGPR, ~124 regs), 4 blocks/CU ----------------
__global__ __launch_bounds__(256, 4) void gemm_scores1_k(
    const signed char* __restrict__ XQ, const signed char* __restrict__ PQ,
    const float* __restrict__ sxr, const float* __restrict__ sp,
    unsigned* __restrict__ gmax) {
  __shared__ __align__(16) signed char lA[2][128 * 64];   // 16 KB
  __shared__ __align__(16) signed char lB[2][128 * 64];   // 16 KB
  __shared__ float ldsR[128];

  int tid = threadIdx.x;                 // 0..255
  int lane = tid & 63, wid = tid >> 6;   // 4 waves
  int wwr = wid >> 1;                    // 0..1 (m half)
  int wwc = wid & 1;                     // 0..1 (n half)
  int fr = lane & 15, fg = lane >> 4;

  // Bijective swizzle: xcd owns 32 m-tiles; within, n_lo(16) fastest, then
  // m(32), then n_hi(2). Co-resident ~128 blocks/XCD span 8m x 16n = 3MB L2-fit.
  int id = blockIdx.x;                   // 0..8191
  int xcd = id & 7;
  int r = id >> 3;                       // 0..1023
  int n_lo = r & 15;
  int m = (r >> 4) & 31;
  int n_hi = r >> 9;                     // 0..1
  int tile_n = n_lo | (n_hi << 4);       // 0..31
  int tile_m = xcd * 32 + m;             // 0..255
  long m0 = (long)tile_m * 128;
  long n0 = (long)tile_n * 128;

  if (tid < 128) ldsR[tid] = sxr[m0 + tid];

  // stage one K-tile: A 8KB + B 8KB = 1024 x 16B chunks; 4 gload16/thread.
  auto stageTile = [&](int buf, int kt) {
    int kk = kt * 64;
#pragma unroll
    for (int i = 0; i < 2; ++i) {
      int chunk = i * 256 + tid;
      int r2 = chunk >> 2, c = chunk & 3;
      int cs = c ^ ((r2 >> 1) & 3);            // pre-swizzled source
      gload16(XQ + (m0 + r2) * (long)D_DIM + kk + cs * 16,
              (void*)(&lA[buf][0] + ((i * 256 + (tid & ~63)) << 4)));
    }
#pragma unroll
    for (int i = 0; i < 2; ++i) {
      int chunk = i * 256 + tid;
      int r2 = chunk >> 2, c = chunk & 3;
      int cs = c ^ ((r2 >> 1) & 3);
      gload16(PQ + (n0 + r2) * (long)D_DIM + kk + cs * 16,
              (void*)(&lB[buf][0] + ((i * 256 + (tid & ~63)) << 4)));
    }
  };

  i32x4 acc[4][4] = {};

  stageTile(0, 0);
  stageTile(1, 1);
  asm volatile("s_waitcnt lgkmcnt(0)" ::: "memory");  // ldsR visible at barrier

  i32x4 aF[4], bF[4];

  for (int kt = 0; kt < 16; ++kt) {
    int cur = kt & 1;
    const signed char* As = &lA[cur][0];
    const signed char* Bs = &lB[cur][0];

    // wait for buf[cur]'s 4 loads (leave next tile's 4 in flight)
    if (kt < 15) {
      asm volatile("s_waitcnt vmcnt(4)" ::: "memory");
    } else {
      asm volatile("s_waitcnt vmcnt(0)" ::: "memory");
    }
    __builtin_amdgcn_s_barrier();

    // ---- P1: read aF[0..3] + bF[0..1]; MFMA (m, n0-1)
#pragma unroll
    for (int mi = 0; mi < 4; ++mi) {
      int row = wwr * 64 + mi * 16 + fr;
      int ck = fg ^ ((row >> 1) & 3);
      aF[mi] = *(const i32x4*)(As + row * 64 + ck * 16);
    }
#pragma unroll
    for (int ni = 0; ni < 2; ++ni) {
      int row = wwc * 64 + ni * 16 + fr;
      int ck = fg ^ ((row >> 1) & 3);
      bF[ni] = *(const i32x4*)(Bs + row * 64 + ck * 16);
    }
    LGK0_SB();
    __builtin_amdgcn_s_setprio(1);
#pragma unroll
    for (int mi = 0; mi < 4; ++mi)
#pragma unroll
      for (int ni = 0; ni < 2; ++ni)
        acc[mi][ni] = __builtin_amdgcn_mfma_i32_16x16x64_i8(
            aF[mi], bF[ni], acc[mi][ni], 0, 0, 0);
    __builtin_amdgcn_s_setprio(0);

    // ---- P2: read bF[2..3]; barrier closes all reads of buf[cur];
    //          stage(kt+2 -> buf[cur]); MFMA (m, n2-3)
#pragma unroll
    for (int ni = 2; ni < 4; ++ni) {
      int row = wwc * 64 + ni * 16 + fr;
      int ck = fg ^ ((row >> 1) & 3);
      bF[ni] = *(const i32x4*)(Bs + row * 64 + ck * 16);
    }
    LGK0_SB();
    __builtin_amdgcn_s_barrier();
    if (kt + 2 < 16) stageTile(cur, kt + 2);
    __builtin_amdgcn_s_setprio(1);
#pragma unroll
    for (int mi = 0; mi < 4; ++mi)
#pragma unroll
      for (int ni = 2; ni < 4; ++ni)
        acc[mi][ni] = __builtin_amdgcn_mfma_i32_16x16x64_i8(
            aF[mi], bF[ni], acc[mi][ni], 0, 0, 0);
    __builtin_amdgcn_s_setprio(0);
  }

  // epilogue: v = acc*sxr[row]*sp[col]; per-wave column max over 64 rows.
  int b = (int)(m0 >> 11);
#pragma unroll
  for (int ni = 0; ni < 4; ++ni) {
    long col = n0 + wwc * 64 + ni * 16 + fr;
    float spc = sp[col];
    float v = -3.0e38f;
#pragma unroll
    for (int mi = 0; mi < 4; ++mi)
#pragma unroll
      for (int j = 0; j < 4; ++j) {
        int row = wwr * 64 + mi * 16 + fg * 4 + j;
        v = fmaxf(v, (float)acc[mi][ni][j] * ldsR[row]);
      }
    v *= spc;
    v = fmaxf(v, __shfl_xor(v, 16));
    v = fmaxf(v, __shfl_xor(v, 32));
    if (fg == 0) {
      atomicMax(&gmax[(long)b * NE + col], encf(v * 0.03125f));
    }
  }
}

// ---------------- K3b: per-batch top-CAND candidate selection (+ zero gmax2) ----------------
__global__ void cand_select_k(const unsigned* __restrict__ gmax,
                              int* __restrict__ candIdx, unsigned* __restrict__ gmax2) {
  __shared__ unsigned enc[NE];
  __shared__ int ic[257];
  int tid = threadIdx.x;
  int lane = tid & 63, w = tid >> 6;
  int zb = blockIdx.x;
  if (tid < CAND) gmax2[zb * CAND + tid] = 0u;
  const unsigned* g = gmax + (size_t)zb * NE;
  for (int i = tid; i < NE; i += 256) enc[i] = g[i];
  __syncthreads();

  unsigned cur = 0;
  for (int bit = 31; bit >= 0; --bit) {
    unsigned cand = cur | (1u << bit);
    int c = 0;
    for (int i = tid; i < NE; i += 256) c += (enc[i] >= cand) ? 1 : 0;
    for (int o = 32; o > 0; o >>= 1) c += __shfl_xor(c, o);
    __syncthreads();
    if (lane == 0) ic[w] = c;
    __syncthreads();
    int tot = ic[0] + ic[1] + ic[2] + ic[3];
    if (tot >= CAND) cur = cand;
  }

  int myc = 0;
  for (int i = tid; i < NE; i += 256) myc += (enc[i] >= cur) ? 1 : 0;
  __syncthreads();
  ic[tid] = myc;
  __syncthreads();
  if (tid == 0) {
    int s = 0;
    for (int t = 0; t < 256; ++t) { int v = ic[t]; ic[t] = s; s += v; }
  }
  __syncthreads();
  int off = ic[tid];
  for (int i = tid; i < NE; i += 256)
    if (enc[i] >= cur) {
      if (off < CAND) candIdx[zb * CAND + off] = i;
      ++off;
    }
}

// ---------------- K3d: EXACT rescore (indirect candidate staging) ----------------
__global__ __launch_bounds__(256, 2) void gemm_rescore_k(
    const float* __restrict__ X, const float* __restrict__ rinvA,
    const unsigned short* __restrict__ PH, const unsigned short* __restrict__ PL,
    const int* __restrict__ candIdx, unsigned* __restrict__ gmax2) {
  __shared__ __align__(16) float lA[128 * 32];
  __shared__ __align__(16) unsigned short lBH[128 * 32], lBL[128 * 32];
  __shared__ float ldsR[128];

  int tid = threadIdx.x;
  int lane = tid & 63, wid = tid >> 6;
  int wr = wid >> 1, wc = wid & 1;
  int fr = lane & 15, fg = lane >> 4;
  int z = blockIdx.z;
  long m0 = (long)blockIdx.x * 128;
  long arow0 = (long)z * SEQ + m0;

  if (tid < 128) ldsR[tid] = rinvA[arow0 + tid];

  long bbase[2];
#pragma unroll
  for (int i = 0; i < 2; ++i) {
    int r = (i * 256 + tid) >> 2;          // 0..127
    bbase[i] = (long)candIdx[z * CAND + r] * D_DIM;
  }

  f32x4 acc[4][4] = {};

  for (int kk = 0; kk < D_DIM; kk += BK) {
#pragma unroll
    for (int i = 0; i < 4; ++i) {
      int chunk = i * 256 + tid;
      int r = chunk >> 3, c = chunk & 7;
      int cs = c ^ (r & 7);
      const float* src = X + (arow0 + r) * (long)D_DIM + kk + cs * 4;
      gload16(src, (void*)(lA + ((i * 256 + (tid & ~63)) << 2)));
    }
#pragma unroll
    for (int i = 0; i < 2; ++i) {
      int chunk = i * 256 + tid;
      int c = chunk & 3;
      int r = chunk >> 2;
      int cs = c ^ ((r >> 1) & 3);
      long boff = bbase[i] + kk + cs * 8;
      int lo = (i * 256 + (tid & ~63)) << 3;
      gload16(PH + boff, (void*)(lBH + lo));
      gload16(PL + boff, (void*)(lBL + lo));
    }
    __syncthreads();

    bf16x8 aH[4], aL[4], bH[4], bL[4];
#pragma unroll
    for (int m = 0; m < 4; ++m) {
      int row = wr * 64 + m * 16 + fr;
      int rm = row & 7;
      f32x4 p0 = *(const f32x4*)(lA + row * 32 + (((fg * 2 + 0) ^ rm) * 4));
      f32x4 p1 = *(const f32x4*)(lA + row * 32 + (((fg * 2 + 1) ^ rm) * 4));
#pragma unroll
      for (int e = 0; e < 8; ++e) {
        float f = (e < 4) ? p0[e] : p1[e - 4];
        unsigned short h = f2bf(f);
        aH[m][e] = (short)h;
        aL[m][e] = (short)f2bf(f - bf2f(h));
      }
    }
#pragma unroll
    for (int n = 0; n < 4; ++n) {
      int row = wc * 64 + n * 16 + fr;
      int sc = fg ^ ((row >> 1) & 3);
      bH[n] = *(const bf16x8*)(lBH + row * 32 + sc * 8);
      bL[n] = *(const bf16x8*)(lBL + row * 32 + sc * 8);
    }
#pragma unroll
    for (int m = 0; m < 4; ++m)
#pragma unroll
      for (int n = 0; n < 4; ++n) {
        acc[m][n] = __builtin_amdgcn_mfma_f32_16x16x32_bf16(aH[m], bH[n], acc[m][n], 0, 0, 0);
        acc[m][n] = __builtin_amdgcn_mfma_f32_16x16x32_bf16(aH[m], bL[n], acc[m][n], 0, 0, 0);
        acc[m][n] = __builtin_amdgcn_mfma_f32_16x16x32_bf16(aL[m], bH[n], acc[m][n], 0, 0, 0);
      }
    __syncthreads();
  }

#pragma unroll
  for (int n = 0; n < 4; ++n) {
    float v = -3.0e38f;
#pragma unroll
    for (int m = 0; m < 4; ++m)
#pragma unroll
      for (int j = 0; j < 4; ++j) {
        float rv = ldsR[wr * 64 + m * 16 + fg * 4 + j];
        v = fmaxf(v, acc[m][n][j] * rv);
      }
    v = fmaxf(v, __shfl_xor(v, 16));
    v = fmaxf(v, __shfl_xor(v, 32));
    if (fg == 0) {
      int col = wc * 64 + n * 16 + fr;
      atomicMax(&gmax2[z * CAND + col], encf(v * 0.03125f));
    }
  }
}

// ---------------- K4: final — patch exact vals, top-64, weights, O ----------------
__global__ void final_k(const unsigned* __restrict__ gmax,
                        const unsigned* __restrict__ gmax2,
                        const int* __restrict__ candIdx,
                        const float* __restrict__ alpha_p,
                        const float* __restrict__ E, const float* __restrict__ rinvE,
                        const float* __restrict__ sn_w, const float* __restrict__ on_w,
                        float* __restrict__ wout, float* __restrict__ O) {
  __shared__ unsigned enc[NE];
  __shared__ int sel[NE];
  __shared__ unsigned ubc[4];
  __shared__ float l4[4];
  __shared__ int ic[257];
  int tid = threadIdx.x;
  int lane = tid & 63, w = tid >> 6;
  int b = blockIdx.x;
  const unsigned* g = gmax + (size_t)b * NE;
  for (int i = tid; i < NE; i += 256) enc[i] = g[i];
  __syncthreads();
  if (tid < CAND) enc[candIdx[b * CAND + tid]] = gmax2[b * CAND + tid];  // exact patch
  __syncthreads();

  unsigned mx = 0;
  for (int i = tid; i < NE; i += 256) mx = enc[i] > mx ? enc[i] : mx;
  for (int o = 32; o > 0; o >>= 1) {
    unsigned other = (unsigned)__shfl_xor((int)mx, o);
    if (other > mx) mx = other;
  }
  if (lane == 0) ubc[w] = mx;
  __syncthreads();
  unsigned m1e = ubc[0];
  for (int t = 1; t < 4; ++t) m1e = ubc[t] > m1e ? ubc[t] : m1e;
  float m1 = decf(m1e);

  unsigned cur = 0;
  for (int bit = 31; bit >= 0; --bit) {
    unsigned cand = cur | (1u << bit);
    int c = 0;
    for (int i = tid; i < NE; i += 256) c += (enc[i] >= cand) ? 1 : 0;
    for (int o = 32; o > 0; o >>= 1) c += __shfl_xor(c, o);
    __syncthreads();
    if (lane == 0) ic[w] = c;
    __syncthreads();
    int tot = ic[0] + ic[1] + ic[2] + ic[3];
    if (tot >= KTOP) cur = cand;
  }

  float sd = 0.f, ssum = 0.f;
  for (int i = tid; i < NE; i += 256) {
    float e = expf(decf(enc[i]) - m1);
    sd += e;
    if (enc[i] >= cur) ssum += e;
  }
  for (int o = 32; o > 0; o >>= 1) { sd += __shfl_xor(sd, o); ssum += __shfl_xor(ssum, o); }
  __syncthreads();
  if (lane == 0) { l4[w] = sd; }
  __syncthreads();
  float SD = l4[0] + l4[1] + l4[2] + l4[3];
  __syncthreads();
  if (lane == 0) { l4[w] = ssum; }
  __syncthreads();
  float SS = l4[0] + l4[1] + l4[2] + l4[3];

  float alpha = alpha_p[0];
  float wd = alpha / SD;
  float ws_ = (1.0f - alpha) / SS;
  for (int i = tid; i < NE; i += 256) {
    float e = expf(decf(enc[i]) - m1);
    float wv = wd * e + ((enc[i] >= cur) ? ws_ * e : 0.0f);
    wout[(size_t)b * NE + i] = wv;
  }

  // compact selected indices into LDS
  int myc = 0;
  for (int i = tid; i < NE; i += 256) myc += (enc[i] >= cur) ? 1 : 0;
  __syncthreads();
  ic[tid] = myc;
  __syncthreads();
  if (tid == 0) {
    int s = 0;
    for (int t = 0; t < 256; ++t) { int v = ic[t]; ic[t] = s; s += v; }
    ic[256] = s;
  }
  __syncthreads();
  int off = ic[tid];
  for (int i = tid; i < NE; i += 256)
    if (enc[i] >= cur) sel[off++] = i;
  __syncthreads();
  int nsel = ic[256];

  // O = rmsnorm(weights @ En, on_w)
  float acc[4] = {0.f, 0.f, 0.f, 0.f};
  if (alpha == 0.0f) {
    float coef = wd + ws_;
    for (int j = 0; j < nsel; ++j) {
      int n = sel[j];
      float e = expf(decf(enc[n]) - m1);
      float wv = coef * e * rinvE[n];
      const float* er = E + (size_t)n * D_DIM;
#pragma unroll
      for (int i = 0; i < 4; ++i) acc[i] += wv * er[tid + 256 * i];
    }
  } else {
    for (int n = 0; n < NE; ++n) {
      float e = expf(decf(enc[n]) - m1);
      float wv = (wd * e + ((enc[n] >= cur) ? ws_ * e : 0.0f)) * rinvE[n];
      const float* er = E + (size_t)n * D_DIM;
#pragma unroll
      for (int i = 0; i < 4; ++i) acc[i] += wv * er[tid + 256 * i];
    }
  }
  float ssq = 0.f;
#pragma unroll
  for (int i = 0; i < 4; ++i) {
    acc[i] *= sn_w[tid + 256 * i];
    ssq += acc[i] * acc[i];
  }
  for (int o = 32; o > 0; o >>= 1) ssq += __shfl_xor(ssq, o);
  if (lane == 0) l4[w] = ssq;
  __syncthreads();
  float tot = l4[0] + l4[1] + l4[2] + l4[3];
  float rn = rsqrtf(tot * (1.0f / D_DIM) + 1e-6f);
#pragma unroll
  for (int i = 0; i < 4; ++i)
    O[(size_t)b * D_DIM + tid + 256 * i] = acc[i] * rn * on_w[tid + 256 * i];
}

}  // namespace

extern "C" void kernel_launch(void* const* d_in, const int* in_sizes, int n_in,
                              void* d_out, int out_size, void* d_ws, size_t ws_size,
                              hipStream_t stream) {
  const float* X     = (const float*)d_in[0];
  const float* alpha = (const float*)d_in[1];
  const float* E     = (const float*)d_in[2];
  const float* Wq    = (const float*)d_in[3];
  const float* Wk    = (const float*)d_in[4];
  const float* xn_w  = (const float*)d_in[5];
  const float* sn_w  = (const float*)d_in[6];
  const float* on_w  = (const float*)d_in[7];
  float* O    = (float*)d_out;                          // [16][1024]
  float* Wout = (float*)d_out + (size_t)BATCH * D_DIM;  // [16][4096]

  char* ws = (char*)d_ws;
  size_t off = 0;
  auto alloc = [&](size_t bytes) {
    char* p = ws + off;
    off += (bytes + 255) & ~(size_t)255;
    return p;
  };
  signed char*    XQ    = (signed char*)alloc((size_t)MX * D_DIM);          // 32 MB
  signed char*    PQ    = (signed char*)alloc((size_t)NE * D_DIM);          // 4 MB
  float*          WqTf  = (float*)alloc((size_t)D_DIM * D_DIM * 4);
  unsigned short* WkTH  = (unsigned short*)alloc((size_t)D_DIM * D_DIM * 2);
  unsigned short* WkTL  = (unsigned short*)alloc((size_t)D_DIM * D_DIM * 2);
  unsigned short* W2TH  = (unsigned short*)alloc((size_t)D_DIM * D_DIM * 2);
  unsigned short* W2TL  = (unsigned short*)alloc((size_t)D_DIM * D_DIM * 2);
  unsigned short* PH    = (unsigned short*)alloc((size_t)NE * D_DIM * 2);
  unsigned short* PL    = (unsigned short*)alloc((size_t)NE * D_DIM * 2);
  float* rinvX = (float*)alloc((size_t)MX * 4);
  float* sxr   = (float*)alloc((size_t)MX * 4);
  float* rinvE = (float*)alloc((size_t)NE * 4);
  float* sp    = (float*)alloc((size_t)NE * 4);
  unsigned* gmax  = (unsigned*)alloc((size_t)BATCH * NE * 4);
  unsigned* gmax2 = (unsigned*)alloc((size_t)BATCH * CAND * 4);
  int* candIdx = (int*)alloc((size_t)BATCH * CAND * 4);
  if (off > ws_size) return;  // needs ~67 MB scratch

  hipMemsetAsync(gmax, 0, (size_t)BATCH * NE * 4, stream);

  row_rinv_k<<<NE, 256, 0, stream>>>(E, rinvE);
  prep_w_k<<<dim3(D_DIM / 32, D_DIM / 32), 256, 0, stream>>>(
      Wq, Wk, sn_w, WqTf, WkTH, WkTL);
  // W2T[j][d] = xn_w[j] * sum_k WqT[j,k] * WkT'[d,k]   (1024^2, 3-product)
  gemm_a32_k<0><<<dim3(8, 8), 256, 0, stream>>>(
      WqTf, xn_w, WkTH, WkTL, W2TH, W2TL, nullptr);
  // P'[n][j] = sum_d (E[n,d]*rinvE[n]) * W2T[j,d]      (4096x1024, 3-product)
  gemm_a32_k<0><<<dim3(NE / 128, D_DIM / 128), 256, 0, stream>>>(
      E, rinvE, W2TH, W2TL, PH, PL, nullptr);
  quant_p_k<<<NE, 256, 0, stream>>>(PH, PL, sp, (int*)PQ);

  rinv_quantx_k<<<MX, 256, 0, stream>>>(X, rinvX, sxr, (int*)XQ);
  gemm_scores1_k<<<(MX / 128) * (NE / 128), 256, 0, stream>>>(XQ, PQ, sxr, sp, gmax);

  cand_select_k<<<BATCH, 256, 0, stream>>>(gmax, candIdx, gmax2);
  gemm_rescore_k<<<dim3(SEQ / 128, 1, BATCH), 256, 0, stream>>>(
      X, rinvX, PH, PL, candIdx, gmax2);
  final_k<<<BATCH, 256, 0, stream>>>(gmax, gmax2, candIdx, alpha, E, rinvE,
                                     sn_w, on_w, Wout, O);
}

// Round 15
// 425.251 us; speedup vs baseline: 1.0317x; 1.0317x over previous
//
#include <hip/hip_runtime.h>

// BasisAttention: B=16,S=2048,D=1024,N=4096,K_TOP=64. fp32 in/out.
// R4: approx-then-rescore. R5: scores = Xn@(Km Wq)^T. R8: weight-chain fusion.
// R9/R11: XCD swizzle + L2-fit co-residency. R10: int8 approx pass.
// R11: indirect rescore staging, merged final_k. R13: 64-AGPR waves, 2 blk/CU.
// R14 refuted occupancy theory (4 blk/CU was WORSE: more atomics, MfmaUtil down).
// R15: remove the blanket lgkmcnt(0)+sched_barrier fences inside the K-tile
//      (they applied rule-18 to PLAIN loads, defeating the compiler's
//      fine-grained lgkmcnt(N) interleave of ds_read and MFMA — m97/G7).
//      Single lgkmcnt(0) kept before the buffer-release barrier only.

namespace {

constexpr int D_DIM = 1024;
constexpr int NE    = 4096;
constexpr int BATCH = 16;
constexpr int SEQ   = 2048;
constexpr int MX    = BATCH * SEQ;   // 32768
constexpr int KTOP  = 64;
constexpr int CAND  = 128;           // candidates per batch
constexpr int BK    = 32;

using f32x4  = __attribute__((ext_vector_type(4))) float;
using bf16x8 = __attribute__((ext_vector_type(8))) short;
using i32x4  = __attribute__((ext_vector_type(4))) int;

__device__ inline unsigned encf(float f) {
  unsigned u = __float_as_uint(f);
  return (u & 0x80000000u) ? ~u : (u | 0x80000000u);
}
__device__ inline float decf(unsigned e) {
  unsigned u = (e & 0x80000000u) ? (e ^ 0x80000000u) : ~e;
  return __uint_as_float(u);
}

__device__ inline unsigned short f2bf(float f) {  // RNE float->bf16 bits
  unsigned u = __float_as_uint(f);
  unsigned lsb = (u >> 16) & 1u;
  u += 0x7fffu + lsb;
  return (unsigned short)(u >> 16);
}
__device__ inline float bf2f(unsigned short h) {
  return __uint_as_float(((unsigned)h) << 16);
}

__device__ inline void gload16(const void* gsrc, void* ldst) {
  __builtin_amdgcn_global_load_lds(
      (const __attribute__((address_space(1))) unsigned int*)gsrc,
      (__attribute__((address_space(3))) unsigned int*)ldst, 16, 0, 0);
}

// ---------------- K1: per-row rsqrt(mean(x^2)+eps) ----------------
__global__ void row_rinv_k(const float* __restrict__ X, float* __restrict__ rinv) {
  __shared__ float l4[4];
  int row = blockIdx.x;
  float4 v = ((const float4*)(X + (size_t)row * D_DIM))[threadIdx.x];
  float ss = v.x * v.x + v.y * v.y + v.z * v.z + v.w * v.w;
  for (int o = 32; o > 0; o >>= 1) ss += __shfl_xor(ss, o);
  int lane = threadIdx.x & 63, w = threadIdx.x >> 6;
  if (lane == 0) l4[w] = ss;
  __syncthreads();
  if (threadIdx.x == 0) {
    float t = l4[0] + l4[1] + l4[2] + l4[3];
    rinv[row] = rsqrtf(t * (1.0f / D_DIM) + 1e-6f);
  }
}

// ---------------- K1a: fused per-row rinv + int8 quant of X ----------------
__global__ void rinv_quantx_k(const float* __restrict__ X, float* __restrict__ rinv,
                              float* __restrict__ sxr, int* __restrict__ XQ) {
  __shared__ float l4[4], m4[4];
  int row = blockIdx.x;
  float4 v = ((const float4*)(X + (size_t)row * D_DIM))[threadIdx.x];
  float ss = v.x * v.x + v.y * v.y + v.z * v.z + v.w * v.w;
  float am = fmaxf(fmaxf(fabsf(v.x), fabsf(v.y)), fmaxf(fabsf(v.z), fabsf(v.w)));
  for (int o = 32; o > 0; o >>= 1) {
    ss += __shfl_xor(ss, o);
    am = fmaxf(am, __shfl_xor(am, o));
  }
  int lane = threadIdx.x & 63, w = threadIdx.x >> 6;
  if (lane == 0) { l4[w] = ss; m4[w] = am; }
  __syncthreads();
  float t  = l4[0] + l4[1] + l4[2] + l4[3];
  float amax = fmaxf(fmaxf(m4[0], m4[1]), fmaxf(m4[2], m4[3]));
  amax = fmaxf(amax, 1e-30f);
  float ri = rsqrtf(t * (1.0f / D_DIM) + 1e-6f);
  if (threadIdx.x == 0) {
    rinv[row] = ri;
    sxr[row]  = ri * amax * (1.0f / 127.0f);
  }
  float qs = 127.0f / amax;
  int q0 = (int)rintf(v.x * qs) & 0xff;
  int q1 = (int)rintf(v.y * qs) & 0xff;
  int q2 = (int)rintf(v.z * qs) & 0xff;
  int q3 = (int)rintf(v.w * qs) & 0xff;
  XQ[(size_t)row * 256 + threadIdx.x] = q0 | (q1 << 8) | (q2 << 16) | (q3 << 24);
}

// ---------------- K1e: int8 quant of P rows (from bf16 hi/lo) ----------------
__global__ void quant_p_k(const unsigned short* __restrict__ PH,
                          const unsigned short* __restrict__ PL,
                          float* __restrict__ sp, int* __restrict__ PQ) {
  __shared__ float m4[4];
  int row = blockIdx.x;
  ushort4 h = *(const ushort4*)(PH + (size_t)row * D_DIM + threadIdx.x * 4);
  ushort4 l = *(const ushort4*)(PL + (size_t)row * D_DIM + threadIdx.x * 4);
  float p0 = bf2f(h.x) + bf2f(l.x);
  float p1 = bf2f(h.y) + bf2f(l.y);
  float p2 = bf2f(h.z) + bf2f(l.z);
  float p3 = bf2f(h.w) + bf2f(l.w);
  float am = fmaxf(fmaxf(fabsf(p0), fabsf(p1)), fmaxf(fabsf(p2), fabsf(p3)));
  for (int o = 32; o > 0; o >>= 1) am = fmaxf(am, __shfl_xor(am, o));
  int lane = threadIdx.x & 63, w = threadIdx.x >> 6;
  if (lane == 0) m4[w] = am;
  __syncthreads();
  float amax = fmaxf(fmaxf(m4[0], m4[1]), fmaxf(m4[2], m4[3]));
  amax = fmaxf(amax, 1e-30f);
  if (threadIdx.x == 0) sp[row] = amax * (1.0f / 127.0f);
  float qs = 127.0f / amax;
  int q0 = (int)rintf(p0 * qs) & 0xff;
  int q1 = (int)rintf(p1 * qs) & 0xff;
  int q2 = (int)rintf(p2 * qs) & 0xff;
  int q3 = (int)rintf(p3 * qs) & 0xff;
  PQ[(size_t)row * 256 + threadIdx.x] = q0 | (q1 << 8) | (q2 << 16) | (q3 << 24);
}

// ---------------- K1b: fused Wq fp32-transpose + Wk scaled bf16-split-transpose ----------------
__global__ void prep_w_k(const float* __restrict__ Wq, const float* __restrict__ Wk,
                         const float* __restrict__ cw, float* __restrict__ T,
                         unsigned short* __restrict__ H, unsigned short* __restrict__ L) {
  __shared__ float t[32][33], u[32][33];
  int k0 = blockIdx.x * 32, d0 = blockIdx.y * 32;
  int tx = threadIdx.x & 31, ty4 = (threadIdx.x >> 5) * 4;
#pragma unroll
  for (int i = 0; i < 4; ++i) {
    t[ty4 + i][tx] = Wq[(size_t)(d0 + ty4 + i) * D_DIM + k0 + tx];
    u[ty4 + i][tx] = Wk[(size_t)(d0 + ty4 + i) * D_DIM + k0 + tx];
  }
  __syncthreads();
#pragma unroll
  for (int i = 0; i < 4; ++i) {
    int a = ty4 + i;
    T[(size_t)(k0 + a) * D_DIM + d0 + tx] = t[tx][a];
    float v = u[tx][a] * cw[k0 + a];
    unsigned short h = f2bf(v);
    H[(size_t)(k0 + a) * D_DIM + d0 + tx] = h;
    L[(size_t)(k0 + a) * D_DIM + d0 + tx] = f2bf(v - bf2f(h));
  }
}

// ---------------- K2: O = rowscale(A_f32) @ B(hi,lo)^T (3-product) ----------------
template <int FPOUT>
__global__ __launch_bounds__(256, 2) void gemm_a32_k(
    const float* __restrict__ A, const float* __restrict__ rinv,
    const unsigned short* __restrict__ BH, const unsigned short* __restrict__ BL,
    unsigned short* __restrict__ OH, unsigned short* __restrict__ OL,
    float* __restrict__ Of) {
  __shared__ __align__(16) float lA[128 * 32];
  __shared__ __align__(16) unsigned short lBH[128 * 32];
  __shared__ __align__(16) unsigned short lBL[128 * 32];
  __shared__ float ldsR[128];

  int tid = threadIdx.x;
  int lane = tid & 63, wid = tid >> 6;
  int wr = wid >> 1, wc = wid & 1;
  int fr = lane & 15, fg = lane >> 4;
  long m0 = (long)blockIdx.x * 128;
  long n0 = (long)blockIdx.y * 128;

  if (tid < 128) ldsR[tid] = rinv ? rinv[m0 + tid] : 1.0f;

  f32x4 acc[4][4] = {};

  for (int kk = 0; kk < D_DIM; kk += BK) {
#pragma unroll
    for (int i = 0; i < 4; ++i) {
      int chunk = i * 256 + tid;
      int r = chunk >> 3, c = chunk & 7;
      int cs = c ^ (r & 7);
      const float* src = A + (m0 + r) * (long)D_DIM + kk + cs * 4;
      gload16(src, (void*)(lA + ((i * 256 + (tid & ~63)) << 2)));
    }
#pragma unroll
    for (int i = 0; i < 2; ++i) {
      int chunk = i * 256 + tid;
      int r = chunk >> 2, c = chunk & 3;
      int cs = c ^ ((r >> 1) & 3);
      long boff = (n0 + r) * (long)D_DIM + kk + cs * 8;
      int lo = (i * 256 + (tid & ~63)) << 3;
      gload16(BH + boff, (void*)(lBH + lo));
      gload16(BL + boff, (void*)(lBL + lo));
    }
    __syncthreads();

    bf16x8 aH[4], aL[4], bH[4], bL[4];
#pragma unroll
    for (int m = 0; m < 4; ++m) {
      int row = wr * 64 + m * 16 + fr;
      int rm = row & 7;
      f32x4 p0 = *(const f32x4*)(lA + row * 32 + (((fg * 2 + 0) ^ rm) * 4));
      f32x4 p1 = *(const f32x4*)(lA + row * 32 + (((fg * 2 + 1) ^ rm) * 4));
#pragma unroll
      for (int e = 0; e < 8; ++e) {
        float f = (e < 4) ? p0[e] : p1[e - 4];
        unsigned short h = f2bf(f);
        aH[m][e] = (short)h;
        aL[m][e] = (short)f2bf(f - bf2f(h));
      }
    }
#pragma unroll
    for (int n = 0; n < 4; ++n) {
      int row = wc * 64 + n * 16 + fr;
      int sc = fg ^ ((row >> 1) & 3);
      bH[n] = *(const bf16x8*)(lBH + row * 32 + sc * 8);
      bL[n] = *(const bf16x8*)(lBL + row * 32 + sc * 8);
    }
#pragma unroll
    for (int m = 0; m < 4; ++m)
#pragma unroll
      for (int n = 0; n < 4; ++n) {
        acc[m][n] = __builtin_amdgcn_mfma_f32_16x16x32_bf16(aH[m], bH[n], acc[m][n], 0, 0, 0);
        acc[m][n] = __builtin_amdgcn_mfma_f32_16x16x32_bf16(aH[m], bL[n], acc[m][n], 0, 0, 0);
        acc[m][n] = __builtin_amdgcn_mfma_f32_16x16x32_bf16(aL[m], bH[n], acc[m][n], 0, 0, 0);
      }
    __syncthreads();
  }

#pragma unroll
  for (int m = 0; m < 4; ++m) {
#pragma unroll
    for (int j = 0; j < 4; ++j) {
      int rloc = wr * 64 + m * 16 + fg * 4 + j;
      float rv = ldsR[rloc];
      long grow = m0 + rloc;
#pragma unroll
      for (int n = 0; n < 4; ++n) {
        long gcol = n0 + wc * 64 + n * 16 + fr;
        float v = acc[m][n][j] * rv;
        if (FPOUT) {
          Of[grow * D_DIM + gcol] = v;
        } else {
          unsigned short h = f2bf(v);
          OH[grow * D_DIM + gcol] = h;
          OL[grow * D_DIM + gcol] = f2bf(v - bf2f(h));
        }
      }
    }
  }
}

// ---------------- K3a: APPROX scores INT8 — 128x256 tile, 8 waves (2m x 4n),
// per-wave 64x64 (acc[4][4]=64 AGPR), compiler-scheduled ds_read/MFMA ----------------
__global__ __launch_bounds__(512, 4) void gemm_scores1_k(
    const signed char* __restrict__ XQ, const signed char* __restrict__ PQ,
    const float* __restrict__ sxr, const float* __restrict__ sp,
    unsigned* __restrict__ gmax) {
  __shared__ __align__(16) signed char lA[2][128 * 64];   // 16 KB
  __shared__ __align__(16) signed char lB[2][256 * 64];   // 32 KB
  __shared__ float ldsR[128];

  int tid = threadIdx.x;                 // 0..511
  int lane = tid & 63, wid = tid >> 6;   // 8 waves
  int wwr = wid >> 2;                    // 0..1  (m half: 64 rows each)
  int wwc = wid & 3;                     // 0..3  (n quarter: 64 cols each)
  int fr = lane & 15, fg = lane >> 4;

  // R13 swizzle: xcd owns 32 m-tiles; within, n fastest -> 8m x 8n co-resident
  // per XCD = 3MB L2-fit.
  int id = blockIdx.x;                   // 0..4095
  int xcd = id & 7;
  int r = id >> 3;                       // 0..511
  int tile_n = (r & 7) | ((r >> 8) << 3);      // 0..15
  int tile_m = xcd * 32 + ((r >> 3) & 31);     // 0..255
  long m0 = (long)tile_m * 128;
  long n0 = (long)tile_n * 256;

  if (tid < 128) ldsR[tid] = sxr[m0 + tid];

  // stage: A 8KB (512 x 16B chunks, 1/thread), B 16KB (1024 chunks, 2/thread)
  auto stageTile = [&](int buf, int kt) {
    int kk = kt * 64;
    {
      int r2 = tid >> 2, c = tid & 3;
      int cs = c ^ ((r2 >> 1) & 3);            // pre-swizzled source
      gload16(XQ + (m0 + r2) * (long)D_DIM + kk + cs * 16,
              (void*)(&lA[buf][0] + ((tid & ~63) << 4)));
    }
#pragma unroll
    for (int i = 0; i < 2; ++i) {
      int chunk = i * 512 + tid;
      int r2 = chunk >> 2, c = chunk & 3;
      int cs = c ^ ((r2 >> 1) & 3);
      gload16(PQ + (n0 + r2) * (long)D_DIM + kk + cs * 16,
              (void*)(&lB[buf][0] + ((i * 512 + (tid & ~63)) << 4)));
    }
  };

  i32x4 acc[4][4] = {};

  stageTile(0, 0);
  stageTile(1, 1);
  asm volatile("s_waitcnt lgkmcnt(0)" ::: "memory");  // ldsR visible at barrier

  for (int kt = 0; kt < 16; ++kt) {
    int cur = kt & 1;
    const signed char* As = &lA[cur][0];
    const signed char* Bs = &lB[cur][0];

    // wait for buf[cur]'s 3 loads (leave next tile's 3 in flight)
    if (kt < 15) {
      asm volatile("s_waitcnt vmcnt(3)" ::: "memory");
    } else {
      asm volatile("s_waitcnt vmcnt(0)" ::: "memory");
    }
    __builtin_amdgcn_s_barrier();

    // read ALL fragments as plain loads; let the compiler interleave the
    // 16 MFMAs with fine-grained lgkmcnt(N) (m97-style scheduling).
    i32x4 aF[4], bF[4];
#pragma unroll
    for (int mi = 0; mi < 4; ++mi) {
      int row = wwr * 64 + mi * 16 + fr;
      int ck = fg ^ ((row >> 1) & 3);
      aF[mi] = *(const i32x4*)(As + row * 64 + ck * 16);
    }
#pragma unroll
    for (int ni = 0; ni < 4; ++ni) {
      int row = wwc * 64 + ni * 16 + fr;
      int ck = fg ^ ((row >> 1) & 3);
      bF[ni] = *(const i32x4*)(Bs + row * 64 + ck * 16);
    }
    __builtin_amdgcn_s_setprio(1);
#pragma unroll
    for (int mi = 0; mi < 4; ++mi)
#pragma unroll
      for (int ni = 0; ni < 4; ++ni)
        acc[mi][ni] = __builtin_amdgcn_mfma_i32_16x16x64_i8(
            aF[mi], bF[ni], acc[mi][ni], 0, 0, 0);
    __builtin_amdgcn_s_setprio(0);

    // all my ds_reads retired (MFMAs consumed them); release buf[cur]
    asm volatile("s_waitcnt lgkmcnt(0)" ::: "memory");
    __builtin_amdgcn_s_barrier();
    if (kt + 2 < 16) stageTile(cur, kt + 2);
  }

  // epilogue: v = acc*sxr[row]*sp[col]; per-wave column max over 64 rows.
  int b = (int)(m0 >> 11);
#pragma unroll
  for (int ni = 0; ni < 4; ++ni) {
    long col = n0 + wwc * 64 + ni * 16 + fr;
    float spc = sp[col];
    float v = -3.0e38f;
#pragma unroll
    for (int mi = 0; mi < 4; ++mi)
#pragma unroll
      for (int j = 0; j < 4; ++j) {
        int row = wwr * 64 + mi * 16 + fg * 4 + j;
        v = fmaxf(v, (float)acc[mi][ni][j] * ldsR[row]);
      }
    v *= spc;
    v = fmaxf(v, __shfl_xor(v, 16));
    v = fmaxf(v, __shfl_xor(v, 32));
    if (fg == 0) {
      atomicMax(&gmax[(long)b * NE + col], encf(v * 0.03125f));
    }
  }
}

// ---------------- K3b: per-batch top-CAND candidate selection (+ zero gmax2) ----------------
__global__ void cand_select_k(const unsigned* __restrict__ gmax,
                              int* __restrict__ candIdx, unsigned* __restrict__ gmax2) {
  __shared__ unsigned enc[NE];
  __shared__ int ic[257];
  int tid = threadIdx.x;
  int lane = tid & 63, w = tid >> 6;
  int zb = blockIdx.x;
  if (tid < CAND) gmax2[zb * CAND + tid] = 0u;
  const unsigned* g = gmax + (size_t)zb * NE;
  for (int i = tid; i < NE; i += 256) enc[i] = g[i];
  __syncthreads();

  unsigned cur = 0;
  for (int bit = 31; bit >= 0; --bit) {
    unsigned cand = cur | (1u << bit);
    int c = 0;
    for (int i = tid; i < NE; i += 256) c += (enc[i] >= cand) ? 1 : 0;
    for (int o = 32; o > 0; o >>= 1) c += __shfl_xor(c, o);
    __syncthreads();
    if (lane == 0) ic[w] = c;
    __syncthreads();
    int tot = ic[0] + ic[1] + ic[2] + ic[3];
    if (tot >= CAND) cur = cand;
  }

  int myc = 0;
  for (int i = tid; i < NE; i += 256) myc += (enc[i] >= cur) ? 1 : 0;
  __syncthreads();
  ic[tid] = myc;
  __syncthreads();
  if (tid == 0) {
    int s = 0;
    for (int t = 0; t < 256; ++t) { int v = ic[t]; ic[t] = s; s += v; }
  }
  __syncthreads();
  int off = ic[tid];
  for (int i = tid; i < NE; i += 256)
    if (enc[i] >= cur) {
      if (off < CAND) candIdx[zb * CAND + off] = i;
      ++off;
    }
}

// ---------------- K3d: EXACT rescore (indirect candidate staging) ----------------
__global__ __launch_bounds__(256, 2) void gemm_rescore_k(
    const float* __restrict__ X, const float* __restrict__ rinvA,
    const unsigned short* __restrict__ PH, const unsigned short* __restrict__ PL,
    const int* __restrict__ candIdx, unsigned* __restrict__ gmax2) {
  __shared__ __align__(16) float lA[128 * 32];
  __shared__ __align__(16) unsigned short lBH[128 * 32], lBL[128 * 32];
  __shared__ float ldsR[128];

  int tid = threadIdx.x;
  int lane = tid & 63, wid = tid >> 6;
  int wr = wid >> 1, wc = wid & 1;
  int fr = lane & 15, fg = lane >> 4;
  int z = blockIdx.z;
  long m0 = (long)blockIdx.x * 128;
  long arow0 = (long)z * SEQ + m0;

  if (tid < 128) ldsR[tid] = rinvA[arow0 + tid];

  long bbase[2];
#pragma unroll
  for (int i = 0; i < 2; ++i) {
    int r = (i * 256 + tid) >> 2;          // 0..127
    bbase[i] = (long)candIdx[z * CAND + r] * D_DIM;
  }

  f32x4 acc[4][4] = {};

  for (int kk = 0; kk < D_DIM; kk += BK) {
#pragma unroll
    for (int i = 0; i < 4; ++i) {
      int chunk = i * 256 + tid;
      int r = chunk >> 3, c = chunk & 7;
      int cs = c ^ (r & 7);
      const float* src = X + (arow0 + r) * (long)D_DIM + kk + cs * 4;
      gload16(src, (void*)(lA + ((i * 256 + (tid & ~63)) << 2)));
    }
#pragma unroll
    for (int i = 0; i < 2; ++i) {
      int chunk = i * 256 + tid;
      int c = chunk & 3;
      int r = chunk >> 2;
      int cs = c ^ ((r >> 1) & 3);
      long boff = bbase[i] + kk + cs * 8;
      int lo = (i * 256 + (tid & ~63)) << 3;
      gload16(PH + boff, (void*)(lBH + lo));
      gload16(PL + boff, (void*)(lBL + lo));
    }
    __syncthreads();

    bf16x8 aH[4], aL[4], bH[4], bL[4];
#pragma unroll
    for (int m = 0; m < 4; ++m) {
      int row = wr * 64 + m * 16 + fr;
      int rm = row & 7;
      f32x4 p0 = *(const f32x4*)(lA + row * 32 + (((fg * 2 + 0) ^ rm) * 4));
      f32x4 p1 = *(const f32x4*)(lA + row * 32 + (((fg * 2 + 1) ^ rm) * 4));
#pragma unroll
      for (int e = 0; e < 8; ++e) {
        float f = (e < 4) ? p0[e] : p1[e - 4];
        unsigned short h = f2bf(f);
        aH[m][e] = (short)h;
        aL[m][e] = (short)f2bf(f - bf2f(h));
      }
    }
#pragma unroll
    for (int n = 0; n < 4; ++n) {
      int row = wc * 64 + n * 16 + fr;
      int sc = fg ^ ((row >> 1) & 3);
      bH[n] = *(const bf16x8*)(lBH + row * 32 + sc * 8);
      bL[n] = *(const bf16x8*)(lBL + row * 32 + sc * 8);
    }
#pragma unroll
    for (int m = 0; m < 4; ++m)
#pragma unroll
      for (int n = 0; n < 4; ++n) {
        acc[m][n] = __builtin_amdgcn_mfma_f32_16x16x32_bf16(aH[m], bH[n], acc[m][n], 0, 0, 0);
        acc[m][n] = __builtin_amdgcn_mfma_f32_16x16x32_bf16(aH[m], bL[n], acc[m][n], 0, 0, 0);
        acc[m][n] = __builtin_amdgcn_mfma_f32_16x16x32_bf16(aL[m], bH[n], acc[m][n], 0, 0, 0);
      }
    __syncthreads();
  }

#pragma unroll
  for (int n = 0; n < 4; ++n) {
    float v = -3.0e38f;
#pragma unroll
    for (int m = 0; m < 4; ++m)
#pragma unroll
      for (int j = 0; j < 4; ++j) {
        float rv = ldsR[wr * 64 + m * 16 + fg * 4 + j];
        v = fmaxf(v, acc[m][n][j] * rv);
      }
    v = fmaxf(v, __shfl_xor(v, 16));
    v = fmaxf(v, __shfl_xor(v, 32));
    if (fg == 0) {
      int col = wc * 64 + n * 16 + fr;
      atomicMax(&gmax2[z * CAND + col], encf(v * 0.03125f));
    }
  }
}

// ---------------- K4: final — patch exact vals, top-64, weights, O ----------------
__global__ void final_k(const unsigned* __restrict__ gmax,
                        const unsigned* __restrict__ gmax2,
                        const int* __restrict__ candIdx,
                        const float* __restrict__ alpha_p,
                        const float* __restrict__ E, const float* __restrict__ rinvE,
                        const float* __restrict__ sn_w, const float* __restrict__ on_w,
                        float* __restrict__ wout, float* __restrict__ O) {
  __shared__ unsigned enc[NE];
  __shared__ int sel[NE];
  __shared__ unsigned ubc[4];
  __shared__ float l4[4];
  __shared__ int ic[257];
  int tid = threadIdx.x;
  int lane = tid & 63, w = tid >> 6;
  int b = blockIdx.x;
  const unsigned* g = gmax + (size_t)b * NE;
  for (int i = tid; i < NE; i += 256) enc[i] = g[i];
  __syncthreads();
  if (tid < CAND) enc[candIdx[b * CAND + tid]] = gmax2[b * CAND + tid];  // exact patch
  __syncthreads();

  unsigned mx = 0;
  for (int i = tid; i < NE; i += 256) mx = enc[i] > mx ? enc[i] : mx;
  for (int o = 32; o > 0; o >>= 1) {
    unsigned other = (unsigned)__shfl_xor((int)mx, o);
    if (other > mx) mx = other;
  }
  if (lane == 0) ubc[w] = mx;
  __syncthreads();
  unsigned m1e = ubc[0];
  for (int t = 1; t < 4; ++t) m1e = ubc[t] > m1e ? ubc[t] : m1e;
  float m1 = decf(m1e);

  unsigned cur = 0;
  for (int bit = 31; bit >= 0; --bit) {
    unsigned cand = cur | (1u << bit);
    int c = 0;
    for (int i = tid; i < NE; i += 256) c += (enc[i] >= cand) ? 1 : 0;
    for (int o = 32; o > 0; o >>= 1) c += __shfl_xor(c, o);
    __syncthreads();
    if (lane == 0) ic[w] = c;
    __syncthreads();
    int tot = ic[0] + ic[1] + ic[2] + ic[3];
    if (tot >= KTOP) cur = cand;
  }

  float sd = 0.f, ssum = 0.f;
  for (int i = tid; i < NE; i += 256) {
    float e = expf(decf(enc[i]) - m1);
    sd += e;
    if (enc[i] >= cur) ssum += e;
  }
  for (int o = 32; o > 0; o >>= 1) { sd += __shfl_xor(sd, o); ssum += __shfl_xor(ssum, o); }
  __syncthreads();
  if (lane == 0) { l4[w] = sd; }
  __syncthreads();
  float SD = l4[0] + l4[1] + l4[2] + l4[3];
  __syncthreads();
  if (lane == 0) { l4[w] = ssum; }
  __syncthreads();
  float SS = l4[0] + l4[1] + l4[2] + l4[3];

  float alpha = alpha_p[0];
  float wd = alpha / SD;
  float ws_ = (1.0f - alpha) / SS;
  for (int i = tid; i < NE; i += 256) {
    float e = expf(decf(enc[i]) - m1);
    float wv = wd * e + ((enc[i] >= cur) ? ws_ * e : 0.0f);
    wout[(size_t)b * NE + i] = wv;
  }

  // compact selected indices into LDS
  int myc = 0;
  for (int i = tid; i < NE; i += 256) myc += (enc[i] >= cur) ? 1 : 0;
  __syncthreads();
  ic[tid] = myc;
  __syncthreads();
  if (tid == 0) {
    int s = 0;
    for (int t = 0; t < 256; ++t) { int v = ic[t]; ic[t] = s; s += v; }
    ic[256] = s;
  }
  __syncthreads();
  int off = ic[tid];
  for (int i = tid; i < NE; i += 256)
    if (enc[i] >= cur) sel[off++] = i;
  __syncthreads();
  int nsel = ic[256];

  // O = rmsnorm(weights @ En, on_w)
  float acc[4] = {0.f, 0.f, 0.f, 0.f};
  if (alpha == 0.0f) {
    float coef = wd + ws_;
    for (int j = 0; j < nsel; ++j) {
      int n = sel[j];
      float e = expf(decf(enc[n]) - m1);
      float wv = coef * e * rinvE[n];
      const float* er = E + (size_t)n * D_DIM;
#pragma unroll
      for (int i = 0; i < 4; ++i) acc[i] += wv * er[tid + 256 * i];
    }
  } else {
    for (int n = 0; n < NE; ++n) {
      float e = expf(decf(enc[n]) - m1);
      float wv = (wd * e + ((enc[n] >= cur) ? ws_ * e : 0.0f)) * rinvE[n];
      const float* er = E + (size_t)n * D_DIM;
#pragma unroll
      for (int i = 0; i < 4; ++i) acc[i] += wv * er[tid + 256 * i];
    }
  }
  float ssq = 0.f;
#pragma unroll
  for (int i = 0; i < 4; ++i) {
    acc[i] *= sn_w[tid + 256 * i];
    ssq += acc[i] * acc[i];
  }
  for (int o = 32; o > 0; o >>= 1) ssq += __shfl_xor(ssq, o);
  if (lane == 0) l4[w] = ssq;
  __syncthreads();
  float tot = l4[0] + l4[1] + l4[2] + l4[3];
  float rn = rsqrtf(tot * (1.0f / D_DIM) + 1e-6f);
#pragma unroll
  for (int i = 0; i < 4; ++i)
    O[(size_t)b * D_DIM + tid + 256 * i] = acc[i] * rn * on_w[tid + 256 * i];
}

}  // namespace

extern "C" void kernel_launch(void* const* d_in, const int* in_sizes, int n_in,
                              void* d_out, int out_size, void* d_ws, size_t ws_size,
                              hipStream_t stream) {
  const float* X     = (const float*)d_in[0];
  const float* alpha = (const float*)d_in[1];
  const float* E     = (const float*)d_in[2];
  const float* Wq    = (const float*)d_in[3];
  const float* Wk    = (const float*)d_in[4];
  const float* xn_w  = (const float*)d_in[5];
  const float* sn_w  = (const float*)d_in[6];
  const float* on_w  = (const float*)d_in[7];
  float* O    = (float*)d_out;                          // [16][1024]
  float* Wout = (float*)d_out + (size_t)BATCH * D_DIM;  // [16][4096]

  char* ws = (char*)d_ws;
  size_t off = 0;
  auto alloc = [&](size_t bytes) {
    char* p = ws + off;
    off += (bytes + 255) & ~(size_t)255;
    return p;
  };
  signed char*    XQ    = (signed char*)alloc((size_t)MX * D_DIM);          // 32 MB
  signed char*    PQ    = (signed char*)alloc((size_t)NE * D_DIM);          // 4 MB
  float*          WqTf  = (float*)alloc((size_t)D_DIM * D_DIM * 4);
  unsigned short* WkTH  = (unsigned short*)alloc((size_t)D_DIM * D_DIM * 2);
  unsigned short* WkTL  = (unsigned short*)alloc((size_t)D_DIM * D_DIM * 2);
  unsigned short* W2TH  = (unsigned short*)alloc((size_t)D_DIM * D_DIM * 2);
  unsigned short* W2TL  = (unsigned short*)alloc((size_t)D_DIM * D_DIM * 2);
  unsigned short* PH    = (unsigned short*)alloc((size_t)NE * D_DIM * 2);
  unsigned short* PL    = (unsigned short*)alloc((size_t)NE * D_DIM * 2);
  float* rinvX = (float*)alloc((size_t)MX * 4);
  float* sxr   = (float*)alloc((size_t)MX * 4);
  float* rinvE = (float*)alloc((size_t)NE * 4);
  float* sp    = (float*)alloc((size_t)NE * 4);
  unsigned* gmax  = (unsigned*)alloc((size_t)BATCH * NE * 4);
  unsigned* gmax2 = (unsigned*)alloc((size_t)BATCH * CAND * 4);
  int* candIdx = (int*)alloc((size_t)BATCH * CAND * 4);
  if (off > ws_size) return;  // needs ~67 MB scratch

  hipMemsetAsync(gmax, 0, (size_t)BATCH * NE * 4, stream);

  row_rinv_k<<<NE, 256, 0, stream>>>(E, rinvE);
  prep_w_k<<<dim3(D_DIM / 32, D_DIM / 32), 256, 0, stream>>>(
      Wq, Wk, sn_w, WqTf, WkTH, WkTL);
  // W2T[j][d] = xn_w[j] * sum_k WqT[j,k] * WkT'[d,k]   (1024^2, 3-product)
  gemm_a32_k<0><<<dim3(8, 8), 256, 0, stream>>>(
      WqTf, xn_w, WkTH, WkTL, W2TH, W2TL, nullptr);
  // P'[n][j] = sum_d (E[n,d]*rinvE[n]) * W2T[j,d]      (4096x1024, 3-product)
  gemm_a32_k<0><<<dim3(NE / 128, D_DIM / 128), 256, 0, stream>>>(
      E, rinvE, W2TH, W2TL, PH, PL, nullptr);
  quant_p_k<<<NE, 256, 0, stream>>>(PH, PL, sp, (int*)PQ);

  rinv_quantx_k<<<MX, 256, 0, stream>>>(X, rinvX, sxr, (int*)XQ);
  gemm_scores1_k<<<(MX / 128) * (NE / 256), 512, 0, stream>>>(XQ, PQ, sxr, sp, gmax);

  cand_select_k<<<BATCH, 256, 0, stream>>>(gmax, candIdx, gmax2);
  gemm_rescore_k<<<dim3(SEQ / 128, 1, BATCH), 256, 0, stream>>>(
      X, rinvX, PH, PL, candIdx, gmax2);
  final_k<<<BATCH, 256, 0, stream>>>(gmax, gmax2, candIdx, alpha, E, rinvE,
                                     sn_w, on_w, Wout, O);
}

// Round 16
// 388.527 us; speedup vs baseline: 1.1292x; 1.0945x over previous
//
#include <hip/hip_runtime.h>

// BasisAttention: B=16,S=2048,D=1024,N=4096,K_TOP=64. fp32 in/out.
// R4: approx-then-rescore. R5: scores = Xn@(Km Wq)^T. R8: weight-chain fusion.
// R9/R11: XCD swizzle + L2-fit co-residency. R10: int8 approx pass.
// R11: indirect rescore staging, merged final_k. R13-R15: scores1 at its
//      2-phase structural floor (~150us; LDS+MFMA serialized ~124us).
// R16: tail attack — weight-chain GEMMs were parallelism-starved
//      (W2T: 64 blocks = 25% CUs ~30us; P: 256 blocks = 1/CU ~50us).
//      K-split partial GEMMs (no atomics; separate fp32 partial buffers)
//      + fused sum/split/quant reducers (absorbs quant_p_k).

namespace {

constexpr int D_DIM = 1024;
constexpr int NE    = 4096;
constexpr int BATCH = 16;
constexpr int SEQ   = 2048;
constexpr int MX    = BATCH * SEQ;   // 32768
constexpr int KTOP  = 64;
constexpr int CAND  = 128;           // candidates per batch
constexpr int BK    = 32;

using f32x4  = __attribute__((ext_vector_type(4))) float;
using bf16x8 = __attribute__((ext_vector_type(8))) short;
using i32x4  = __attribute__((ext_vector_type(4))) int;

__device__ inline unsigned encf(float f) {
  unsigned u = __float_as_uint(f);
  return (u & 0x80000000u) ? ~u : (u | 0x80000000u);
}
__device__ inline float decf(unsigned e) {
  unsigned u = (e & 0x80000000u) ? (e ^ 0x80000000u) : ~e;
  return __uint_as_float(u);
}

__device__ inline unsigned short f2bf(float f) {  // RNE float->bf16 bits
  unsigned u = __float_as_uint(f);
  unsigned lsb = (u >> 16) & 1u;
  u += 0x7fffu + lsb;
  return (unsigned short)(u >> 16);
}
__device__ inline float bf2f(unsigned short h) {
  return __uint_as_float(((unsigned)h) << 16);
}

__device__ inline void gload16(const void* gsrc, void* ldst) {
  __builtin_amdgcn_global_load_lds(
      (const __attribute__((address_space(1))) unsigned int*)gsrc,
      (__attribute__((address_space(3))) unsigned int*)ldst, 16, 0, 0);
}

// ---------------- K1: per-row rsqrt(mean(x^2)+eps) ----------------
__global__ void row_rinv_k(const float* __restrict__ X, float* __restrict__ rinv) {
  __shared__ float l4[4];
  int row = blockIdx.x;
  float4 v = ((const float4*)(X + (size_t)row * D_DIM))[threadIdx.x];
  float ss = v.x * v.x + v.y * v.y + v.z * v.z + v.w * v.w;
  for (int o = 32; o > 0; o >>= 1) ss += __shfl_xor(ss, o);
  int lane = threadIdx.x & 63, w = threadIdx.x >> 6;
  if (lane == 0) l4[w] = ss;
  __syncthreads();
  if (threadIdx.x == 0) {
    float t = l4[0] + l4[1] + l4[2] + l4[3];
    rinv[row] = rsqrtf(t * (1.0f / D_DIM) + 1e-6f);
  }
}

// ---------------- K1a: fused per-row rinv + int8 quant of X ----------------
__global__ void rinv_quantx_k(const float* __restrict__ X, float* __restrict__ rinv,
                              float* __restrict__ sxr, int* __restrict__ XQ) {
  __shared__ float l4[4], m4[4];
  int row = blockIdx.x;
  float4 v = ((const float4*)(X + (size_t)row * D_DIM))[threadIdx.x];
  float ss = v.x * v.x + v.y * v.y + v.z * v.z + v.w * v.w;
  float am = fmaxf(fmaxf(fabsf(v.x), fabsf(v.y)), fmaxf(fabsf(v.z), fabsf(v.w)));
  for (int o = 32; o > 0; o >>= 1) {
    ss += __shfl_xor(ss, o);
    am = fmaxf(am, __shfl_xor(am, o));
  }
  int lane = threadIdx.x & 63, w = threadIdx.x >> 6;
  if (lane == 0) { l4[w] = ss; m4[w] = am; }
  __syncthreads();
  float t  = l4[0] + l4[1] + l4[2] + l4[3];
  float amax = fmaxf(fmaxf(m4[0], m4[1]), fmaxf(m4[2], m4[3]));
  amax = fmaxf(amax, 1e-30f);
  float ri = rsqrtf(t * (1.0f / D_DIM) + 1e-6f);
  if (threadIdx.x == 0) {
    rinv[row] = ri;
    sxr[row]  = ri * amax * (1.0f / 127.0f);
  }
  float qs = 127.0f / amax;
  int q0 = (int)rintf(v.x * qs) & 0xff;
  int q1 = (int)rintf(v.y * qs) & 0xff;
  int q2 = (int)rintf(v.z * qs) & 0xff;
  int q3 = (int)rintf(v.w * qs) & 0xff;
  XQ[(size_t)row * 256 + threadIdx.x] = q0 | (q1 << 8) | (q2 << 16) | (q3 << 24);
}

// ---------------- K1b: fused Wq fp32-transpose + Wk scaled bf16-split-transpose ----------------
__global__ void prep_w_k(const float* __restrict__ Wq, const float* __restrict__ Wk,
                         const float* __restrict__ cw, float* __restrict__ T,
                         unsigned short* __restrict__ H, unsigned short* __restrict__ L) {
  __shared__ float t[32][33], u[32][33];
  int k0 = blockIdx.x * 32, d0 = blockIdx.y * 32;
  int tx = threadIdx.x & 31, ty4 = (threadIdx.x >> 5) * 4;
#pragma unroll
  for (int i = 0; i < 4; ++i) {
    t[ty4 + i][tx] = Wq[(size_t)(d0 + ty4 + i) * D_DIM + k0 + tx];
    u[ty4 + i][tx] = Wk[(size_t)(d0 + ty4 + i) * D_DIM + k0 + tx];
  }
  __syncthreads();
#pragma unroll
  for (int i = 0; i < 4; ++i) {
    int a = ty4 + i;
    T[(size_t)(k0 + a) * D_DIM + d0 + tx] = t[tx][a];
    float v = u[tx][a] * cw[k0 + a];
    unsigned short h = f2bf(v);
    H[(size_t)(k0 + a) * D_DIM + d0 + tx] = h;
    L[(size_t)(k0 + a) * D_DIM + d0 + tx] = f2bf(v - bf2f(h));
  }
}

// ---------------- K2: PARTIAL O = rowscale(A_f32) @ B(hi,lo)^T over K-slice ----------------
// z = blockIdx.z selects K-slice [z*KLEN, (z+1)*KLEN); writes fp32 partial to
// Of + z * (gridDim.x*128*1024).
template <int KLEN>
__global__ __launch_bounds__(256, 2) void gemm_a32_part_k(
    const float* __restrict__ A, const float* __restrict__ rinv,
    const unsigned short* __restrict__ BH, const unsigned short* __restrict__ BL,
    float* __restrict__ Of) {
  __shared__ __align__(16) float lA[128 * 32];
  __shared__ __align__(16) unsigned short lBH[128 * 32];
  __shared__ __align__(16) unsigned short lBL[128 * 32];
  __shared__ float ldsR[128];

  int tid = threadIdx.x;
  int lane = tid & 63, wid = tid >> 6;
  int wr = wid >> 1, wc = wid & 1;
  int fr = lane & 15, fg = lane >> 4;
  long m0 = (long)blockIdx.x * 128;
  long n0 = (long)blockIdx.y * 128;
  int kbeg = blockIdx.z * KLEN;
  float* Op = Of + (size_t)blockIdx.z * ((size_t)gridDim.x * 128 * D_DIM);

  if (tid < 128) ldsR[tid] = rinv ? rinv[m0 + tid] : 1.0f;

  f32x4 acc[4][4] = {};

  for (int kk = kbeg; kk < kbeg + KLEN; kk += BK) {
#pragma unroll
    for (int i = 0; i < 4; ++i) {
      int chunk = i * 256 + tid;
      int r = chunk >> 3, c = chunk & 7;
      int cs = c ^ (r & 7);
      const float* src = A + (m0 + r) * (long)D_DIM + kk + cs * 4;
      gload16(src, (void*)(lA + ((i * 256 + (tid & ~63)) << 2)));
    }
#pragma unroll
    for (int i = 0; i < 2; ++i) {
      int chunk = i * 256 + tid;
      int r = chunk >> 2, c = chunk & 3;
      int cs = c ^ ((r >> 1) & 3);
      long boff = (n0 + r) * (long)D_DIM + kk + cs * 8;
      int lo = (i * 256 + (tid & ~63)) << 3;
      gload16(BH + boff, (void*)(lBH + lo));
      gload16(BL + boff, (void*)(lBL + lo));
    }
    __syncthreads();

    bf16x8 aH[4], aL[4], bH[4], bL[4];
#pragma unroll
    for (int m = 0; m < 4; ++m) {
      int row = wr * 64 + m * 16 + fr;
      int rm = row & 7;
      f32x4 p0 = *(const f32x4*)(lA + row * 32 + (((fg * 2 + 0) ^ rm) * 4));
      f32x4 p1 = *(const f32x4*)(lA + row * 32 + (((fg * 2 + 1) ^ rm) * 4));
#pragma unroll
      for (int e = 0; e < 8; ++e) {
        float f = (e < 4) ? p0[e] : p1[e - 4];
        unsigned short h = f2bf(f);
        aH[m][e] = (short)h;
        aL[m][e] = (short)f2bf(f - bf2f(h));
      }
    }
#pragma unroll
    for (int n = 0; n < 4; ++n) {
      int row = wc * 64 + n * 16 + fr;
      int sc = fg ^ ((row >> 1) & 3);
      bH[n] = *(const bf16x8*)(lBH + row * 32 + sc * 8);
      bL[n] = *(const bf16x8*)(lBL + row * 32 + sc * 8);
    }
#pragma unroll
    for (int m = 0; m < 4; ++m)
#pragma unroll
      for (int n = 0; n < 4; ++n) {
        acc[m][n] = __builtin_amdgcn_mfma_f32_16x16x32_bf16(aH[m], bH[n], acc[m][n], 0, 0, 0);
        acc[m][n] = __builtin_amdgcn_mfma_f32_16x16x32_bf16(aH[m], bL[n], acc[m][n], 0, 0, 0);
        acc[m][n] = __builtin_amdgcn_mfma_f32_16x16x32_bf16(aL[m], bH[n], acc[m][n], 0, 0, 0);
      }
    __syncthreads();
  }

#pragma unroll
  for (int m = 0; m < 4; ++m) {
#pragma unroll
    for (int j = 0; j < 4; ++j) {
      int rloc = wr * 64 + m * 16 + fg * 4 + j;
      float rv = ldsR[rloc];
      long grow = m0 + rloc;
#pragma unroll
      for (int n = 0; n < 4; ++n) {
        long gcol = n0 + wc * 64 + n * 16 + fr;
        Op[grow * D_DIM + gcol] = acc[m][n][j] * rv;
      }
    }
  }
}

// ---------------- K2b: sum 4 partials -> bf16 hi/lo split (W2T) ----------------
__global__ void sum_split_w2_k(const float* __restrict__ P0, const float* __restrict__ P1,
                               const float* __restrict__ P2, const float* __restrict__ P3,
                               unsigned short* __restrict__ H, unsigned short* __restrict__ L) {
  size_t i4 = ((size_t)blockIdx.x * 256 + threadIdx.x) * 4;
  float4 a = *(const float4*)(P0 + i4);
  float4 b = *(const float4*)(P1 + i4);
  float4 c = *(const float4*)(P2 + i4);
  float4 d = *(const float4*)(P3 + i4);
  float v[4] = {a.x + b.x + c.x + d.x, a.y + b.y + c.y + d.y,
                a.z + b.z + c.z + d.z, a.w + b.w + c.w + d.w};
  unsigned short h[4], l[4];
#pragma unroll
  for (int i = 0; i < 4; ++i) {
    h[i] = f2bf(v[i]);
    l[i] = f2bf(v[i] - bf2f(h[i]));
  }
  *(ushort4*)(H + i4) = make_ushort4(h[0], h[1], h[2], h[3]);
  *(ushort4*)(L + i4) = make_ushort4(l[0], l[1], l[2], l[3]);
}

// ---------------- K2c: sum 2 partials -> PH/PL split + row amax + int8 PQ ----------------
__global__ void sum_split_p_k(const float* __restrict__ P0, const float* __restrict__ P1,
                              unsigned short* __restrict__ PH, unsigned short* __restrict__ PL,
                              float* __restrict__ sp, int* __restrict__ PQ) {
  __shared__ float m4[4];
  int row = blockIdx.x, tid = threadIdx.x;
  size_t i4 = (size_t)row * D_DIM + tid * 4;
  float4 a = *(const float4*)(P0 + i4);
  float4 b = *(const float4*)(P1 + i4);
  float v0 = a.x + b.x, v1 = a.y + b.y, v2 = a.z + b.z, v3 = a.w + b.w;
  unsigned short h0 = f2bf(v0), h1 = f2bf(v1), h2 = f2bf(v2), h3 = f2bf(v3);
  *(ushort4*)(PH + i4) = make_ushort4(h0, h1, h2, h3);
  *(ushort4*)(PL + i4) = make_ushort4(f2bf(v0 - bf2f(h0)), f2bf(v1 - bf2f(h1)),
                                      f2bf(v2 - bf2f(h2)), f2bf(v3 - bf2f(h3)));
  float am = fmaxf(fmaxf(fabsf(v0), fabsf(v1)), fmaxf(fabsf(v2), fabsf(v3)));
  for (int o = 32; o > 0; o >>= 1) am = fmaxf(am, __shfl_xor(am, o));
  int lane = tid & 63, w = tid >> 6;
  if (lane == 0) m4[w] = am;
  __syncthreads();
  float amax = fmaxf(fmaxf(m4[0], m4[1]), fmaxf(m4[2], m4[3]));
  amax = fmaxf(amax, 1e-30f);
  if (tid == 0) sp[row] = amax * (1.0f / 127.0f);
  float qs = 127.0f / amax;
  int q0 = (int)rintf(v0 * qs) & 0xff;
  int q1 = (int)rintf(v1 * qs) & 0xff;
  int q2 = (int)rintf(v2 * qs) & 0xff;
  int q3 = (int)rintf(v3 * qs) & 0xff;
  PQ[(size_t)row * 256 + tid] = q0 | (q1 << 8) | (q2 << 16) | (q3 << 24);
}

// ---------------- K3a: APPROX scores INT8 — 128x256 tile, 8 waves (2m x 4n) ----------------
__global__ __launch_bounds__(512, 4) void gemm_scores1_k(
    const signed char* __restrict__ XQ, const signed char* __restrict__ PQ,
    const float* __restrict__ sxr, const float* __restrict__ sp,
    unsigned* __restrict__ gmax) {
  __shared__ __align__(16) signed char lA[2][128 * 64];   // 16 KB
  __shared__ __align__(16) signed char lB[2][256 * 64];   // 32 KB
  __shared__ float ldsR[128];

  int tid = threadIdx.x;                 // 0..511
  int lane = tid & 63, wid = tid >> 6;   // 8 waves
  int wwr = wid >> 2;                    // 0..1  (m half: 64 rows each)
  int wwc = wid & 3;                     // 0..3  (n quarter: 64 cols each)
  int fr = lane & 15, fg = lane >> 4;

  int id = blockIdx.x;                   // 0..4095
  int xcd = id & 7;
  int r = id >> 3;                       // 0..511
  int tile_n = (r & 7) | ((r >> 8) << 3);      // 0..15
  int tile_m = xcd * 32 + ((r >> 3) & 31);     // 0..255
  long m0 = (long)tile_m * 128;
  long n0 = (long)tile_n * 256;

  if (tid < 128) ldsR[tid] = sxr[m0 + tid];

  auto stageTile = [&](int buf, int kt) {
    int kk = kt * 64;
    {
      int r2 = tid >> 2, c = tid & 3;
      int cs = c ^ ((r2 >> 1) & 3);            // pre-swizzled source
      gload16(XQ + (m0 + r2) * (long)D_DIM + kk + cs * 16,
              (void*)(&lA[buf][0] + ((tid & ~63) << 4)));
    }
#pragma unroll
    for (int i = 0; i < 2; ++i) {
      int chunk = i * 512 + tid;
      int r2 = chunk >> 2, c = chunk & 3;
      int cs = c ^ ((r2 >> 1) & 3);
      gload16(PQ + (n0 + r2) * (long)D_DIM + kk + cs * 16,
              (void*)(&lB[buf][0] + ((i * 512 + (tid & ~63)) << 4)));
    }
  };

  i32x4 acc[4][4] = {};

  stageTile(0, 0);
  stageTile(1, 1);
  asm volatile("s_waitcnt lgkmcnt(0)" ::: "memory");  // ldsR visible at barrier

  for (int kt = 0; kt < 16; ++kt) {
    int cur = kt & 1;
    const signed char* As = &lA[cur][0];
    const signed char* Bs = &lB[cur][0];

    if (kt < 15) {
      asm volatile("s_waitcnt vmcnt(3)" ::: "memory");
    } else {
      asm volatile("s_waitcnt vmcnt(0)" ::: "memory");
    }
    __builtin_amdgcn_s_barrier();

    i32x4 aF[4], bF[4];
#pragma unroll
    for (int mi = 0; mi < 4; ++mi) {
      int row = wwr * 64 + mi * 16 + fr;
      int ck = fg ^ ((row >> 1) & 3);
      aF[mi] = *(const i32x4*)(As + row * 64 + ck * 16);
    }
#pragma unroll
    for (int ni = 0; ni < 4; ++ni) {
      int row = wwc * 64 + ni * 16 + fr;
      int ck = fg ^ ((row >> 1) & 3);
      bF[ni] = *(const i32x4*)(Bs + row * 64 + ck * 16);
    }
    __builtin_amdgcn_s_setprio(1);
#pragma unroll
    for (int mi = 0; mi < 4; ++mi)
#pragma unroll
      for (int ni = 0; ni < 4; ++ni)
        acc[mi][ni] = __builtin_amdgcn_mfma_i32_16x16x64_i8(
            aF[mi], bF[ni], acc[mi][ni], 0, 0, 0);
    __builtin_amdgcn_s_setprio(0);

    asm volatile("s_waitcnt lgkmcnt(0)" ::: "memory");
    __builtin_amdgcn_s_barrier();
    if (kt + 2 < 16) stageTile(cur, kt + 2);
  }

  int b = (int)(m0 >> 11);
#pragma unroll
  for (int ni = 0; ni < 4; ++ni) {
    long col = n0 + wwc * 64 + ni * 16 + fr;
    float spc = sp[col];
    float v = -3.0e38f;
#pragma unroll
    for (int mi = 0; mi < 4; ++mi)
#pragma unroll
      for (int j = 0; j < 4; ++j) {
        int row = wwr * 64 + mi * 16 + fg * 4 + j;
        v = fmaxf(v, (float)acc[mi][ni][j] * ldsR[row]);
      }
    v *= spc;
    v = fmaxf(v, __shfl_xor(v, 16));
    v = fmaxf(v, __shfl_xor(v, 32));
    if (fg == 0) {
      atomicMax(&gmax[(long)b * NE + col], encf(v * 0.03125f));
    }
  }
}

// ---------------- K3b: per-batch top-CAND candidate selection (+ zero gmax2) ----------------
__global__ void cand_select_k(const unsigned* __restrict__ gmax,
                              int* __restrict__ candIdx, unsigned* __restrict__ gmax2) {
  __shared__ unsigned enc[NE];
  __shared__ int ic[257];
  int tid = threadIdx.x;
  int lane = tid & 63, w = tid >> 6;
  int zb = blockIdx.x;
  if (tid < CAND) gmax2[zb * CAND + tid] = 0u;
  const unsigned* g = gmax + (size_t)zb * NE;
  for (int i = tid; i < NE; i += 256) enc[i] = g[i];
  __syncthreads();

  unsigned cur = 0;
  for (int bit = 31; bit >= 0; --bit) {
    unsigned cand = cur | (1u << bit);
    int c = 0;
    for (int i = tid; i < NE; i += 256) c += (enc[i] >= cand) ? 1 : 0;
    for (int o = 32; o > 0; o >>= 1) c += __shfl_xor(c, o);
    __syncthreads();
    if (lane == 0) ic[w] = c;
    __syncthreads();
    int tot = ic[0] + ic[1] + ic[2] + ic[3];
    if (tot >= CAND) cur = cand;
  }

  int myc = 0;
  for (int i = tid; i < NE; i += 256) myc += (enc[i] >= cur) ? 1 : 0;
  __syncthreads();
  ic[tid] = myc;
  __syncthreads();
  if (tid == 0) {
    int s = 0;
    for (int t = 0; t < 256; ++t) { int v = ic[t]; ic[t] = s; s += v; }
  }
  __syncthreads();
  int off = ic[tid];
  for (int i = tid; i < NE; i += 256)
    if (enc[i] >= cur) {
      if (off < CAND) candIdx[zb * CAND + off] = i;
      ++off;
    }
}

// ---------------- K3d: EXACT rescore (indirect candidate staging) ----------------
__global__ __launch_bounds__(256, 2) void gemm_rescore_k(
    const float* __restrict__ X, const float* __restrict__ rinvA,
    const unsigned short* __restrict__ PH, const unsigned short* __restrict__ PL,
    const int* __restrict__ candIdx, unsigned* __restrict__ gmax2) {
  __shared__ __align__(16) float lA[128 * 32];
  __shared__ __align__(16) unsigned short lBH[128 * 32], lBL[128 * 32];
  __shared__ float ldsR[128];

  int tid = threadIdx.x;
  int lane = tid & 63, wid = tid >> 6;
  int wr = wid >> 1, wc = wid & 1;
  int fr = lane & 15, fg = lane >> 4;
  int z = blockIdx.z;
  long m0 = (long)blockIdx.x * 128;
  long arow0 = (long)z * SEQ + m0;

  if (tid < 128) ldsR[tid] = rinvA[arow0 + tid];

  long bbase[2];
#pragma unroll
  for (int i = 0; i < 2; ++i) {
    int r = (i * 256 + tid) >> 2;          // 0..127
    bbase[i] = (long)candIdx[z * CAND + r] * D_DIM;
  }

  f32x4 acc[4][4] = {};

  for (int kk = 0; kk < D_DIM; kk += BK) {
#pragma unroll
    for (int i = 0; i < 4; ++i) {
      int chunk = i * 256 + tid;
      int r = chunk >> 3, c = chunk & 7;
      int cs = c ^ (r & 7);
      const float* src = X + (arow0 + r) * (long)D_DIM + kk + cs * 4;
      gload16(src, (void*)(lA + ((i * 256 + (tid & ~63)) << 2)));
    }
#pragma unroll
    for (int i = 0; i < 2; ++i) {
      int chunk = i * 256 + tid;
      int c = chunk & 3;
      int r = chunk >> 2;
      int cs = c ^ ((r >> 1) & 3);
      long boff = bbase[i] + kk + cs * 8;
      int lo = (i * 256 + (tid & ~63)) << 3;
      gload16(PH + boff, (void*)(lBH + lo));
      gload16(PL + boff, (void*)(lBL + lo));
    }
    __syncthreads();

    bf16x8 aH[4], aL[4], bH[4], bL[4];
#pragma unroll
    for (int m = 0; m < 4; ++m) {
      int row = wr * 64 + m * 16 + fr;
      int rm = row & 7;
      f32x4 p0 = *(const f32x4*)(lA + row * 32 + (((fg * 2 + 0) ^ rm) * 4));
      f32x4 p1 = *(const f32x4*)(lA + row * 32 + (((fg * 2 + 1) ^ rm) * 4));
#pragma unroll
      for (int e = 0; e < 8; ++e) {
        float f = (e < 4) ? p0[e] : p1[e - 4];
        unsigned short h = f2bf(f);
        aH[m][e] = (short)h;
        aL[m][e] = (short)f2bf(f - bf2f(h));
      }
    }
#pragma unroll
    for (int n = 0; n < 4; ++n) {
      int row = wc * 64 + n * 16 + fr;
      int sc = fg ^ ((row >> 1) & 3);
      bH[n] = *(const bf16x8*)(lBH + row * 32 + sc * 8);
      bL[n] = *(const bf16x8*)(lBL + row * 32 + sc * 8);
    }
#pragma unroll
    for (int m = 0; m < 4; ++m)
#pragma unroll
      for (int n = 0; n < 4; ++n) {
        acc[m][n] = __builtin_amdgcn_mfma_f32_16x16x32_bf16(aH[m], bH[n], acc[m][n], 0, 0, 0);
        acc[m][n] = __builtin_amdgcn_mfma_f32_16x16x32_bf16(aH[m], bL[n], acc[m][n], 0, 0, 0);
        acc[m][n] = __builtin_amdgcn_mfma_f32_16x16x32_bf16(aL[m], bH[n], acc[m][n], 0, 0, 0);
      }
    __syncthreads();
  }

#pragma unroll
  for (int n = 0; n < 4; ++n) {
    float v = -3.0e38f;
#pragma unroll
    for (int m = 0; m < 4; ++m)
#pragma unroll
      for (int j = 0; j < 4; ++j) {
        float rv = ldsR[wr * 64 + m * 16 + fg * 4 + j];
        v = fmaxf(v, acc[m][n][j] * rv);
      }
    v = fmaxf(v, __shfl_xor(v, 16));
    v = fmaxf(v, __shfl_xor(v, 32));
    if (fg == 0) {
      int col = wc * 64 + n * 16 + fr;
      atomicMax(&gmax2[z * CAND + col], encf(v * 0.03125f));
    }
  }
}

// ---------------- K4: final — patch exact vals, top-64, weights, O ----------------
__global__ void final_k(const unsigned* __restrict__ gmax,
                        const unsigned* __restrict__ gmax2,
                        const int* __restrict__ candIdx,
                        const float* __restrict__ alpha_p,
                        const float* __restrict__ E, const float* __restrict__ rinvE,
                        const float* __restrict__ sn_w, const float* __restrict__ on_w,
                        float* __restrict__ wout, float* __restrict__ O) {
  __shared__ unsigned enc[NE];
  __shared__ int sel[NE];
  __shared__ unsigned ubc[4];
  __shared__ float l4[4];
  __shared__ int ic[257];
  int tid = threadIdx.x;
  int lane = tid & 63, w = tid >> 6;
  int b = blockIdx.x;
  const unsigned* g = gmax + (size_t)b * NE;
  for (int i = tid; i < NE; i += 256) enc[i] = g[i];
  __syncthreads();
  if (tid < CAND) enc[candIdx[b * CAND + tid]] = gmax2[b * CAND + tid];  // exact patch
  __syncthreads();

  unsigned mx = 0;
  for (int i = tid; i < NE; i += 256) mx = enc[i] > mx ? enc[i] : mx;
  for (int o = 32; o > 0; o >>= 1) {
    unsigned other = (unsigned)__shfl_xor((int)mx, o);
    if (other > mx) mx = other;
  }
  if (lane == 0) ubc[w] = mx;
  __syncthreads();
  unsigned m1e = ubc[0];
  for (int t = 1; t < 4; ++t) m1e = ubc[t] > m1e ? ubc[t] : m1e;
  float m1 = decf(m1e);

  unsigned cur = 0;
  for (int bit = 31; bit >= 0; --bit) {
    unsigned cand = cur | (1u << bit);
    int c = 0;
    for (int i = tid; i < NE; i += 256) c += (enc[i] >= cand) ? 1 : 0;
    for (int o = 32; o > 0; o >>= 1) c += __shfl_xor(c, o);
    __syncthreads();
    if (lane == 0) ic[w] = c;
    __syncthreads();
    int tot = ic[0] + ic[1] + ic[2] + ic[3];
    if (tot >= KTOP) cur = cand;
  }

  float sd = 0.f, ssum = 0.f;
  for (int i = tid; i < NE; i += 256) {
    float e = expf(decf(enc[i]) - m1);
    sd += e;
    if (enc[i] >= cur) ssum += e;
  }
  for (int o = 32; o > 0; o >>= 1) { sd += __shfl_xor(sd, o); ssum += __shfl_xor(ssum, o); }
  __syncthreads();
  if (lane == 0) { l4[w] = sd; }
  __syncthreads();
  float SD = l4[0] + l4[1] + l4[2] + l4[3];
  __syncthreads();
  if (lane == 0) { l4[w] = ssum; }
  __syncthreads();
  float SS = l4[0] + l4[1] + l4[2] + l4[3];

  float alpha = alpha_p[0];
  float wd = alpha / SD;
  float ws_ = (1.0f - alpha) / SS;
  for (int i = tid; i < NE; i += 256) {
    float e = expf(decf(enc[i]) - m1);
    float wv = wd * e + ((enc[i] >= cur) ? ws_ * e : 0.0f);
    wout[(size_t)b * NE + i] = wv;
  }

  // compact selected indices into LDS
  int myc = 0;
  for (int i = tid; i < NE; i += 256) myc += (enc[i] >= cur) ? 1 : 0;
  __syncthreads();
  ic[tid] = myc;
  __syncthreads();
  if (tid == 0) {
    int s = 0;
    for (int t = 0; t < 256; ++t) { int v = ic[t]; ic[t] = s; s += v; }
    ic[256] = s;
  }
  __syncthreads();
  int off = ic[tid];
  for (int i = tid; i < NE; i += 256)
    if (enc[i] >= cur) sel[off++] = i;
  __syncthreads();
  int nsel = ic[256];

  // O = rmsnorm(weights @ En, on_w)
  float acc[4] = {0.f, 0.f, 0.f, 0.f};
  if (alpha == 0.0f) {
    float coef = wd + ws_;
    for (int j = 0; j < nsel; ++j) {
      int n = sel[j];
      float e = expf(decf(enc[n]) - m1);
      float wv = coef * e * rinvE[n];
      const float* er = E + (size_t)n * D_DIM;
#pragma unroll
      for (int i = 0; i < 4; ++i) acc[i] += wv * er[tid + 256 * i];
    }
  } else {
    for (int n = 0; n < NE; ++n) {
      float e = expf(decf(enc[n]) - m1);
      float wv = (wd * e + ((enc[n] >= cur) ? ws_ * e : 0.0f)) * rinvE[n];
      const float* er = E + (size_t)n * D_DIM;
#pragma unroll
      for (int i = 0; i < 4; ++i) acc[i] += wv * er[tid + 256 * i];
    }
  }
  float ssq = 0.f;
#pragma unroll
  for (int i = 0; i < 4; ++i) {
    acc[i] *= sn_w[tid + 256 * i];
    ssq += acc[i] * acc[i];
  }
  for (int o = 32; o > 0; o >>= 1) ssq += __shfl_xor(ssq, o);
  if (lane == 0) l4[w] = ssq;
  __syncthreads();
  float tot = l4[0] + l4[1] + l4[2] + l4[3];
  float rn = rsqrtf(tot * (1.0f / D_DIM) + 1e-6f);
#pragma unroll
  for (int i = 0; i < 4; ++i)
    O[(size_t)b * D_DIM + tid + 256 * i] = acc[i] * rn * on_w[tid + 256 * i];
}

}  // namespace

extern "C" void kernel_launch(void* const* d_in, const int* in_sizes, int n_in,
                              void* d_out, int out_size, void* d_ws, size_t ws_size,
                              hipStream_t stream) {
  const float* X     = (const float*)d_in[0];
  const float* alpha = (const float*)d_in[1];
  const float* E     = (const float*)d_in[2];
  const float* Wq    = (const float*)d_in[3];
  const float* Wk    = (const float*)d_in[4];
  const float* xn_w  = (const float*)d_in[5];
  const float* sn_w  = (const float*)d_in[6];
  const float* on_w  = (const float*)d_in[7];
  float* O    = (float*)d_out;                          // [16][1024]
  float* Wout = (float*)d_out + (size_t)BATCH * D_DIM;  // [16][4096]

  char* ws = (char*)d_ws;
  size_t off = 0;
  auto alloc = [&](size_t bytes) {
    char* p = ws + off;
    off += (bytes + 255) & ~(size_t)255;
    return p;
  };
  signed char*    XQ    = (signed char*)alloc((size_t)MX * D_DIM);          // 32 MB
  signed char*    PQ    = (signed char*)alloc((size_t)NE * D_DIM);          // 4 MB
  float*          WqTf  = (float*)alloc((size_t)D_DIM * D_DIM * 4);
  unsigned short* WkTH  = (unsigned short*)alloc((size_t)D_DIM * D_DIM * 2);
  unsigned short* WkTL  = (unsigned short*)alloc((size_t)D_DIM * D_DIM * 2);
  unsigned short* W2TH  = (unsigned short*)alloc((size_t)D_DIM * D_DIM * 2);
  unsigned short* W2TL  = (unsigned short*)alloc((size_t)D_DIM * D_DIM * 2);
  unsigned short* PH    = (unsigned short*)alloc((size_t)NE * D_DIM * 2);
  unsigned short* PL    = (unsigned short*)alloc((size_t)NE * D_DIM * 2);
  float*          W2p   = (float*)alloc((size_t)4 * D_DIM * D_DIM * 4);     // 16 MB
  float*          Pp    = (float*)alloc((size_t)2 * NE * D_DIM * 4);        // 32 MB
  float* rinvX = (float*)alloc((size_t)MX * 4);
  float* sxr   = (float*)alloc((size_t)MX * 4);
  float* rinvE = (float*)alloc((size_t)NE * 4);
  float* sp    = (float*)alloc((size_t)NE * 4);
  unsigned* gmax  = (unsigned*)alloc((size_t)BATCH * NE * 4);
  unsigned* gmax2 = (unsigned*)alloc((size_t)BATCH * CAND * 4);
  int* candIdx = (int*)alloc((size_t)BATCH * CAND * 4);
  if (off > ws_size) return;  // needs ~115 MB scratch

  hipMemsetAsync(gmax, 0, (size_t)BATCH * NE * 4, stream);

  row_rinv_k<<<NE, 256, 0, stream>>>(E, rinvE);
  prep_w_k<<<dim3(D_DIM / 32, D_DIM / 32), 256, 0, stream>>>(
      Wq, Wk, sn_w, WqTf, WkTH, WkTL);
  // W2T[j][d] = xn_w[j] * sum_k WqT[j,k] * WkT'[d,k]  — K-split z=4, 256 blocks
  gemm_a32_part_k<256><<<dim3(8, 8, 4), 256, 0, stream>>>(
      WqTf, xn_w, WkTH, WkTL, W2p);
  sum_split_w2_k<<<D_DIM * D_DIM / 1024, 256, 0, stream>>>(
      W2p, W2p + (size_t)D_DIM * D_DIM, W2p + (size_t)2 * D_DIM * D_DIM,
      W2p + (size_t)3 * D_DIM * D_DIM, W2TH, W2TL);
  // P'[n][j] = sum_d (E[n,d]*rinvE[n]) * W2T[j,d]  — K-split z=2, 512 blocks
  gemm_a32_part_k<512><<<dim3(NE / 128, D_DIM / 128, 2), 256, 0, stream>>>(
      E, rinvE, W2TH, W2TL, Pp);
  sum_split_p_k<<<NE, 256, 0, stream>>>(
      Pp, Pp + (size_t)NE * D_DIM, PH, PL, sp, (int*)PQ);

  rinv_quantx_k<<<MX, 256, 0, stream>>>(X, rinvX, sxr, (int*)XQ);
  gemm_scores1_k<<<(MX / 128) * (NE / 256), 512, 0, stream>>>(XQ, PQ, sxr, sp, gmax);

  cand_select_k<<<BATCH, 256, 0, stream>>>(gmax, candIdx, gmax2);
  gemm_rescore_k<<<dim3(SEQ / 128, 1, BATCH), 256, 0, stream>>>(
      X, rinvX, PH, PL, candIdx, gmax2);
  final_k<<<BATCH, 256, 0, stream>>>(gmax, gmax2, candIdx, alpha, E, rinvE,
                                     sn_w, on_w, Wout, O);
}

// Round 17
// 381.444 us; speedup vs baseline: 1.1502x; 1.0186x over previous
//
#include <hip/hip_runtime.h>

// BasisAttention: B=16,S=2048,D=1024,N=4096,K_TOP=64. fp32 in/out.
// R4: approx-then-rescore. R5: scores = Xn@(Km Wq)^T. R8: weight-chain fusion.
// R9/R11: XCD swizzle + L2-fit co-residency. R10: int8 approx pass.
// R11: indirect rescore staging, merged final_k. R16: K-split weight GEMMs.
// R17: (a) scores1 3-buffer/ONE-barrier K-loop (release barrier provably
//      redundant: MFMAs retire the reads before the next arrival barrier);
//      stage issued before compute. (b) early-exit binary search (count==K
//      -> set identical to reference mask) in cand_select/final_k.

namespace {

constexpr int D_DIM = 1024;
constexpr int NE    = 4096;
constexpr int BATCH = 16;
constexpr int SEQ   = 2048;
constexpr int MX    = BATCH * SEQ;   // 32768
constexpr int KTOP  = 64;
constexpr int CAND  = 128;           // candidates per batch
constexpr int BK    = 32;

using f32x4  = __attribute__((ext_vector_type(4))) float;
using bf16x8 = __attribute__((ext_vector_type(8))) short;
using i32x4  = __attribute__((ext_vector_type(4))) int;

__device__ inline unsigned encf(float f) {
  unsigned u = __float_as_uint(f);
  return (u & 0x80000000u) ? ~u : (u | 0x80000000u);
}
__device__ inline float decf(unsigned e) {
  unsigned u = (e & 0x80000000u) ? (e ^ 0x80000000u) : ~e;
  return __uint_as_float(u);
}

__device__ inline unsigned short f2bf(float f) {  // RNE float->bf16 bits
  unsigned u = __float_as_uint(f);
  unsigned lsb = (u >> 16) & 1u;
  u += 0x7fffu + lsb;
  return (unsigned short)(u >> 16);
}
__device__ inline float bf2f(unsigned short h) {
  return __uint_as_float(((unsigned)h) << 16);
}

__device__ inline void gload16(const void* gsrc, void* ldst) {
  __builtin_amdgcn_global_load_lds(
      (const __attribute__((address_space(1))) unsigned int*)gsrc,
      (__attribute__((address_space(3))) unsigned int*)ldst, 16, 0, 0);
}

// ---------------- K1: per-row rsqrt(mean(x^2)+eps) ----------------
__global__ void row_rinv_k(const float* __restrict__ X, float* __restrict__ rinv) {
  __shared__ float l4[4];
  int row = blockIdx.x;
  float4 v = ((const float4*)(X + (size_t)row * D_DIM))[threadIdx.x];
  float ss = v.x * v.x + v.y * v.y + v.z * v.z + v.w * v.w;
  for (int o = 32; o > 0; o >>= 1) ss += __shfl_xor(ss, o);
  int lane = threadIdx.x & 63, w = threadIdx.x >> 6;
  if (lane == 0) l4[w] = ss;
  __syncthreads();
  if (threadIdx.x == 0) {
    float t = l4[0] + l4[1] + l4[2] + l4[3];
    rinv[row] = rsqrtf(t * (1.0f / D_DIM) + 1e-6f);
  }
}

// ---------------- K1a: fused per-row rinv + int8 quant of X ----------------
__global__ void rinv_quantx_k(const float* __restrict__ X, float* __restrict__ rinv,
                              float* __restrict__ sxr, int* __restrict__ XQ) {
  __shared__ float l4[4], m4[4];
  int row = blockIdx.x;
  float4 v = ((const float4*)(X + (size_t)row * D_DIM))[threadIdx.x];
  float ss = v.x * v.x + v.y * v.y + v.z * v.z + v.w * v.w;
  float am = fmaxf(fmaxf(fabsf(v.x), fabsf(v.y)), fmaxf(fabsf(v.z), fabsf(v.w)));
  for (int o = 32; o > 0; o >>= 1) {
    ss += __shfl_xor(ss, o);
    am = fmaxf(am, __shfl_xor(am, o));
  }
  int lane = threadIdx.x & 63, w = threadIdx.x >> 6;
  if (lane == 0) { l4[w] = ss; m4[w] = am; }
  __syncthreads();
  float t  = l4[0] + l4[1] + l4[2] + l4[3];
  float amax = fmaxf(fmaxf(m4[0], m4[1]), fmaxf(m4[2], m4[3]));
  amax = fmaxf(amax, 1e-30f);
  float ri = rsqrtf(t * (1.0f / D_DIM) + 1e-6f);
  if (threadIdx.x == 0) {
    rinv[row] = ri;
    sxr[row]  = ri * amax * (1.0f / 127.0f);
  }
  float qs = 127.0f / amax;
  int q0 = (int)rintf(v.x * qs) & 0xff;
  int q1 = (int)rintf(v.y * qs) & 0xff;
  int q2 = (int)rintf(v.z * qs) & 0xff;
  int q3 = (int)rintf(v.w * qs) & 0xff;
  XQ[(size_t)row * 256 + threadIdx.x] = q0 | (q1 << 8) | (q2 << 16) | (q3 << 24);
}

// ---------------- K1b: fused Wq fp32-transpose + Wk scaled bf16-split-transpose ----------------
__global__ void prep_w_k(const float* __restrict__ Wq, const float* __restrict__ Wk,
                         const float* __restrict__ cw, float* __restrict__ T,
                         unsigned short* __restrict__ H, unsigned short* __restrict__ L) {
  __shared__ float t[32][33], u[32][33];
  int k0 = blockIdx.x * 32, d0 = blockIdx.y * 32;
  int tx = threadIdx.x & 31, ty4 = (threadIdx.x >> 5) * 4;
#pragma unroll
  for (int i = 0; i < 4; ++i) {
    t[ty4 + i][tx] = Wq[(size_t)(d0 + ty4 + i) * D_DIM + k0 + tx];
    u[ty4 + i][tx] = Wk[(size_t)(d0 + ty4 + i) * D_DIM + k0 + tx];
  }
  __syncthreads();
#pragma unroll
  for (int i = 0; i < 4; ++i) {
    int a = ty4 + i;
    T[(size_t)(k0 + a) * D_DIM + d0 + tx] = t[tx][a];
    float v = u[tx][a] * cw[k0 + a];
    unsigned short h = f2bf(v);
    H[(size_t)(k0 + a) * D_DIM + d0 + tx] = h;
    L[(size_t)(k0 + a) * D_DIM + d0 + tx] = f2bf(v - bf2f(h));
  }
}

// ---------------- K2: PARTIAL O = rowscale(A_f32) @ B(hi,lo)^T over K-slice ----------------
template <int KLEN>
__global__ __launch_bounds__(256, 2) void gemm_a32_part_k(
    const float* __restrict__ A, const float* __restrict__ rinv,
    const unsigned short* __restrict__ BH, const unsigned short* __restrict__ BL,
    float* __restrict__ Of) {
  __shared__ __align__(16) float lA[128 * 32];
  __shared__ __align__(16) unsigned short lBH[128 * 32];
  __shared__ __align__(16) unsigned short lBL[128 * 32];
  __shared__ float ldsR[128];

  int tid = threadIdx.x;
  int lane = tid & 63, wid = tid >> 6;
  int wr = wid >> 1, wc = wid & 1;
  int fr = lane & 15, fg = lane >> 4;
  long m0 = (long)blockIdx.x * 128;
  long n0 = (long)blockIdx.y * 128;
  int kbeg = blockIdx.z * KLEN;
  float* Op = Of + (size_t)blockIdx.z * ((size_t)gridDim.x * 128 * D_DIM);

  if (tid < 128) ldsR[tid] = rinv ? rinv[m0 + tid] : 1.0f;

  f32x4 acc[4][4] = {};

  for (int kk = kbeg; kk < kbeg + KLEN; kk += BK) {
#pragma unroll
    for (int i = 0; i < 4; ++i) {
      int chunk = i * 256 + tid;
      int r = chunk >> 3, c = chunk & 7;
      int cs = c ^ (r & 7);
      const float* src = A + (m0 + r) * (long)D_DIM + kk + cs * 4;
      gload16(src, (void*)(lA + ((i * 256 + (tid & ~63)) << 2)));
    }
#pragma unroll
    for (int i = 0; i < 2; ++i) {
      int chunk = i * 256 + tid;
      int r = chunk >> 2, c = chunk & 3;
      int cs = c ^ ((r >> 1) & 3);
      long boff = (n0 + r) * (long)D_DIM + kk + cs * 8;
      int lo = (i * 256 + (tid & ~63)) << 3;
      gload16(BH + boff, (void*)(lBH + lo));
      gload16(BL + boff, (void*)(lBL + lo));
    }
    __syncthreads();

    bf16x8 aH[4], aL[4], bH[4], bL[4];
#pragma unroll
    for (int m = 0; m < 4; ++m) {
      int row = wr * 64 + m * 16 + fr;
      int rm = row & 7;
      f32x4 p0 = *(const f32x4*)(lA + row * 32 + (((fg * 2 + 0) ^ rm) * 4));
      f32x4 p1 = *(const f32x4*)(lA + row * 32 + (((fg * 2 + 1) ^ rm) * 4));
#pragma unroll
      for (int e = 0; e < 8; ++e) {
        float f = (e < 4) ? p0[e] : p1[e - 4];
        unsigned short h = f2bf(f);
        aH[m][e] = (short)h;
        aL[m][e] = (short)f2bf(f - bf2f(h));
      }
    }
#pragma unroll
    for (int n = 0; n < 4; ++n) {
      int row = wc * 64 + n * 16 + fr;
      int sc = fg ^ ((row >> 1) & 3);
      bH[n] = *(const bf16x8*)(lBH + row * 32 + sc * 8);
      bL[n] = *(const bf16x8*)(lBL + row * 32 + sc * 8);
    }
#pragma unroll
    for (int m = 0; m < 4; ++m)
#pragma unroll
      for (int n = 0; n < 4; ++n) {
        acc[m][n] = __builtin_amdgcn_mfma_f32_16x16x32_bf16(aH[m], bH[n], acc[m][n], 0, 0, 0);
        acc[m][n] = __builtin_amdgcn_mfma_f32_16x16x32_bf16(aH[m], bL[n], acc[m][n], 0, 0, 0);
        acc[m][n] = __builtin_amdgcn_mfma_f32_16x16x32_bf16(aL[m], bH[n], acc[m][n], 0, 0, 0);
      }
    __syncthreads();
  }

#pragma unroll
  for (int m = 0; m < 4; ++m) {
#pragma unroll
    for (int j = 0; j < 4; ++j) {
      int rloc = wr * 64 + m * 16 + fg * 4 + j;
      float rv = ldsR[rloc];
      long grow = m0 + rloc;
#pragma unroll
      for (int n = 0; n < 4; ++n) {
        long gcol = n0 + wc * 64 + n * 16 + fr;
        Op[grow * D_DIM + gcol] = acc[m][n][j] * rv;
      }
    }
  }
}

// ---------------- K2b: sum 4 partials -> bf16 hi/lo split (W2T) ----------------
__global__ void sum_split_w2_k(const float* __restrict__ P0, const float* __restrict__ P1,
                               const float* __restrict__ P2, const float* __restrict__ P3,
                               unsigned short* __restrict__ H, unsigned short* __restrict__ L) {
  size_t i4 = ((size_t)blockIdx.x * 256 + threadIdx.x) * 4;
  float4 a = *(const float4*)(P0 + i4);
  float4 b = *(const float4*)(P1 + i4);
  float4 c = *(const float4*)(P2 + i4);
  float4 d = *(const float4*)(P3 + i4);
  float v[4] = {a.x + b.x + c.x + d.x, a.y + b.y + c.y + d.y,
                a.z + b.z + c.z + d.z, a.w + b.w + c.w + d.w};
  unsigned short h[4], l[4];
#pragma unroll
  for (int i = 0; i < 4; ++i) {
    h[i] = f2bf(v[i]);
    l[i] = f2bf(v[i] - bf2f(h[i]));
  }
  *(ushort4*)(H + i4) = make_ushort4(h[0], h[1], h[2], h[3]);
  *(ushort4*)(L + i4) = make_ushort4(l[0], l[1], l[2], l[3]);
}

// ---------------- K2c: sum 2 partials -> PH/PL split + row amax + int8 PQ ----------------
__global__ void sum_split_p_k(const float* __restrict__ P0, const float* __restrict__ P1,
                              unsigned short* __restrict__ PH, unsigned short* __restrict__ PL,
                              float* __restrict__ sp, int* __restrict__ PQ) {
  __shared__ float m4[4];
  int row = blockIdx.x, tid = threadIdx.x;
  size_t i4 = (size_t)row * D_DIM + tid * 4;
  float4 a = *(const float4*)(P0 + i4);
  float4 b = *(const float4*)(P1 + i4);
  float v0 = a.x + b.x, v1 = a.y + b.y, v2 = a.z + b.z, v3 = a.w + b.w;
  unsigned short h0 = f2bf(v0), h1 = f2bf(v1), h2 = f2bf(v2), h3 = f2bf(v3);
  *(ushort4*)(PH + i4) = make_ushort4(h0, h1, h2, h3);
  *(ushort4*)(PL + i4) = make_ushort4(f2bf(v0 - bf2f(h0)), f2bf(v1 - bf2f(h1)),
                                      f2bf(v2 - bf2f(h2)), f2bf(v3 - bf2f(h3)));
  float am = fmaxf(fmaxf(fabsf(v0), fabsf(v1)), fmaxf(fabsf(v2), fabsf(v3)));
  for (int o = 32; o > 0; o >>= 1) am = fmaxf(am, __shfl_xor(am, o));
  int lane = tid & 63, w = tid >> 6;
  if (lane == 0) m4[w] = am;
  __syncthreads();
  float amax = fmaxf(fmaxf(m4[0], m4[1]), fmaxf(m4[2], m4[3]));
  amax = fmaxf(amax, 1e-30f);
  if (tid == 0) sp[row] = amax * (1.0f / 127.0f);
  float qs = 127.0f / amax;
  int q0 = (int)rintf(v0 * qs) & 0xff;
  int q1 = (int)rintf(v1 * qs) & 0xff;
  int q2 = (int)rintf(v2 * qs) & 0xff;
  int q3 = (int)rintf(v3 * qs) & 0xff;
  PQ[(size_t)row * 256 + tid] = q0 | (q1 << 8) | (q2 << 16) | (q3 << 24);
}

// ---------------- K3a: APPROX scores INT8 — 128x256 tile, 8 waves (2m x 4n),
// 3 LDS buffers, ONE barrier per K-tile ----------------
__global__ __launch_bounds__(512, 4) void gemm_scores1_k(
    const signed char* __restrict__ XQ, const signed char* __restrict__ PQ,
    const float* __restrict__ sxr, const float* __restrict__ sp,
    unsigned* __restrict__ gmax) {
  __shared__ __align__(16) signed char lA[3][128 * 64];   // 24 KB
  __shared__ __align__(16) signed char lB[3][256 * 64];   // 48 KB
  __shared__ float ldsR[128];

  int tid = threadIdx.x;                 // 0..511
  int lane = tid & 63, wid = tid >> 6;   // 8 waves
  int wwr = wid >> 2;                    // 0..1  (m half: 64 rows each)
  int wwc = wid & 3;                     // 0..3  (n quarter: 64 cols each)
  int fr = lane & 15, fg = lane >> 4;

  int id = blockIdx.x;                   // 0..4095
  int xcd = id & 7;
  int r = id >> 3;                       // 0..511
  int tile_n = (r & 7) | ((r >> 8) << 3);      // 0..15
  int tile_m = xcd * 32 + ((r >> 3) & 31);     // 0..255
  long m0 = (long)tile_m * 128;
  long n0 = (long)tile_n * 256;

  if (tid < 128) ldsR[tid] = sxr[m0 + tid];

  // stage: A 8KB (512 x 16B chunks, 1/thread), B 16KB (1024 chunks, 2/thread)
  auto stageTile = [&](int buf, int kt) {
    int kk = kt * 64;
    {
      int r2 = tid >> 2, c = tid & 3;
      int cs = c ^ ((r2 >> 1) & 3);            // pre-swizzled source
      gload16(XQ + (m0 + r2) * (long)D_DIM + kk + cs * 16,
              (void*)(&lA[buf][0] + ((tid & ~63) << 4)));
    }
#pragma unroll
    for (int i = 0; i < 2; ++i) {
      int chunk = i * 512 + tid;
      int r2 = chunk >> 2, c = chunk & 3;
      int cs = c ^ ((r2 >> 1) & 3);
      gload16(PQ + (n0 + r2) * (long)D_DIM + kk + cs * 16,
              (void*)(&lB[buf][0] + ((i * 512 + (tid & ~63)) << 4)));
    }
  };

  i32x4 acc[4][4] = {};

  stageTile(0, 0);
  stageTile(1, 1);
  asm volatile("s_waitcnt lgkmcnt(0)" ::: "memory");  // ldsR visible at barrier

  int cur = 0, nxt = 2;                  // kt%3, (kt+2)%3
  for (int kt = 0; kt < 16; ++kt) {
    const signed char* As = &lA[cur][0];
    const signed char* Bs = &lB[cur][0];

    // wait for buf[cur]'s 3 loads (stage(kt+1)'s 3 stay in flight)
    if (kt < 15) {
      asm volatile("s_waitcnt vmcnt(3)" ::: "memory");
    } else {
      asm volatile("s_waitcnt vmcnt(0)" ::: "memory");
    }
    __builtin_amdgcn_s_barrier();
    // single barrier: all waves' kt-1 reads retired (consumed by MFMAs),
    // so buf[nxt] (== buf[(kt-1)%3]) is safe to overwrite now.
    if (kt + 2 < 16) stageTile(nxt, kt + 2);

    i32x4 aF[4], bF[4];
#pragma unroll
    for (int mi = 0; mi < 4; ++mi) {
      int row = wwr * 64 + mi * 16 + fr;
      int ck = fg ^ ((row >> 1) & 3);
      aF[mi] = *(const i32x4*)(As + row * 64 + ck * 16);
    }
#pragma unroll
    for (int ni = 0; ni < 4; ++ni) {
      int row = wwc * 64 + ni * 16 + fr;
      int ck = fg ^ ((row >> 1) & 3);
      bF[ni] = *(const i32x4*)(Bs + row * 64 + ck * 16);
    }
    __builtin_amdgcn_s_setprio(1);
#pragma unroll
    for (int mi = 0; mi < 4; ++mi)
#pragma unroll
      for (int ni = 0; ni < 4; ++ni)
        acc[mi][ni] = __builtin_amdgcn_mfma_i32_16x16x64_i8(
            aF[mi], bF[ni], acc[mi][ni], 0, 0, 0);
    __builtin_amdgcn_s_setprio(0);

    cur = (cur == 2) ? 0 : cur + 1;
    nxt = (nxt == 2) ? 0 : nxt + 1;
  }

  // epilogue: v = acc*sxr[row]*sp[col]; per-wave column max over 64 rows.
  int b = (int)(m0 >> 11);
#pragma unroll
  for (int ni = 0; ni < 4; ++ni) {
    long col = n0 + wwc * 64 + ni * 16 + fr;
    float spc = sp[col];
    float v = -3.0e38f;
#pragma unroll
    for (int mi = 0; mi < 4; ++mi)
#pragma unroll
      for (int j = 0; j < 4; ++j) {
        int row = wwr * 64 + mi * 16 + fg * 4 + j;
        v = fmaxf(v, (float)acc[mi][ni][j] * ldsR[row]);
      }
    v *= spc;
    v = fmaxf(v, __shfl_xor(v, 16));
    v = fmaxf(v, __shfl_xor(v, 32));
    if (fg == 0) {
      atomicMax(&gmax[(long)b * NE + col], encf(v * 0.03125f));
    }
  }
}

// ---------------- K3b: per-batch top-CAND candidate selection (+ zero gmax2) ----------------
__global__ void cand_select_k(const unsigned* __restrict__ gmax,
                              int* __restrict__ candIdx, unsigned* __restrict__ gmax2) {
  __shared__ unsigned enc[NE];
  __shared__ int ic[257];
  int tid = threadIdx.x;
  int lane = tid & 63, w = tid >> 6;
  int zb = blockIdx.x;
  if (tid < CAND) gmax2[zb * CAND + tid] = 0u;
  const unsigned* g = gmax + (size_t)zb * NE;
  for (int i = tid; i < NE; i += 256) enc[i] = g[i];
  __syncthreads();

  unsigned cur = 0;
  for (int bit = 31; bit >= 0; --bit) {
    unsigned cand = cur | (1u << bit);
    int c = 0;
    for (int i = tid; i < NE; i += 256) c += (enc[i] >= cand) ? 1 : 0;
    for (int o = 32; o > 0; o >>= 1) c += __shfl_xor(c, o);
    __syncthreads();
    if (lane == 0) ic[w] = c;
    __syncthreads();
    int tot = ic[0] + ic[1] + ic[2] + ic[3];
    if (tot >= CAND) cur = cand;
    if (tot == CAND) break;   // set {enc>=cand} is exactly the top-CAND
  }

  int myc = 0;
  for (int i = tid; i < NE; i += 256) myc += (enc[i] >= cur) ? 1 : 0;
  __syncthreads();
  ic[tid] = myc;
  __syncthreads();
  if (tid == 0) {
    int s = 0;
    for (int t = 0; t < 256; ++t) { int v = ic[t]; ic[t] = s; s += v; }
  }
  __syncthreads();
  int off = ic[tid];
  for (int i = tid; i < NE; i += 256)
    if (enc[i] >= cur) {
      if (off < CAND) candIdx[zb * CAND + off] = i;
      ++off;
    }
}

// ---------------- K3d: EXACT rescore (indirect candidate staging) ----------------
__global__ __launch_bounds__(256, 2) void gemm_rescore_k(
    const float* __restrict__ X, const float* __restrict__ rinvA,
    const unsigned short* __restrict__ PH, const unsigned short* __restrict__ PL,
    const int* __restrict__ candIdx, unsigned* __restrict__ gmax2) {
  __shared__ __align__(16) float lA[128 * 32];
  __shared__ __align__(16) unsigned short lBH[128 * 32], lBL[128 * 32];
  __shared__ float ldsR[128];

  int tid = threadIdx.x;
  int lane = tid & 63, wid = tid >> 6;
  int wr = wid >> 1, wc = wid & 1;
  int fr = lane & 15, fg = lane >> 4;
  int z = blockIdx.z;
  long m0 = (long)blockIdx.x * 128;
  long arow0 = (long)z * SEQ + m0;

  if (tid < 128) ldsR[tid] = rinvA[arow0 + tid];

  long bbase[2];
#pragma unroll
  for (int i = 0; i < 2; ++i) {
    int r = (i * 256 + tid) >> 2;          // 0..127
    bbase[i] = (long)candIdx[z * CAND + r] * D_DIM;
  }

  f32x4 acc[4][4] = {};

  for (int kk = 0; kk < D_DIM; kk += BK) {
#pragma unroll
    for (int i = 0; i < 4; ++i) {
      int chunk = i * 256 + tid;
      int r = chunk >> 3, c = chunk & 7;
      int cs = c ^ (r & 7);
      const float* src = X + (arow0 + r) * (long)D_DIM + kk + cs * 4;
      gload16(src, (void*)(lA + ((i * 256 + (tid & ~63)) << 2)));
    }
#pragma unroll
    for (int i = 0; i < 2; ++i) {
      int chunk = i * 256 + tid;
      int c = chunk & 3;
      int r = chunk >> 2;
      int cs = c ^ ((r >> 1) & 3);
      long boff = bbase[i] + kk + cs * 8;
      int lo = (i * 256 + (tid & ~63)) << 3;
      gload16(PH + boff, (void*)(lBH + lo));
      gload16(PL + boff, (void*)(lBL + lo));
    }
    __syncthreads();

    bf16x8 aH[4], aL[4], bH[4], bL[4];
#pragma unroll
    for (int m = 0; m < 4; ++m) {
      int row = wr * 64 + m * 16 + fr;
      int rm = row & 7;
      f32x4 p0 = *(const f32x4*)(lA + row * 32 + (((fg * 2 + 0) ^ rm) * 4));
      f32x4 p1 = *(const f32x4*)(lA + row * 32 + (((fg * 2 + 1) ^ rm) * 4));
#pragma unroll
      for (int e = 0; e < 8; ++e) {
        float f = (e < 4) ? p0[e] : p1[e - 4];
        unsigned short h = f2bf(f);
        aH[m][e] = (short)h;
        aL[m][e] = (short)f2bf(f - bf2f(h));
      }
    }
#pragma unroll
    for (int n = 0; n < 4; ++n) {
      int row = wc * 64 + n * 16 + fr;
      int sc = fg ^ ((row >> 1) & 3);
      bH[n] = *(const bf16x8*)(lBH + row * 32 + sc * 8);
      bL[n] = *(const bf16x8*)(lBL + row * 32 + sc * 8);
    }
#pragma unroll
    for (int m = 0; m < 4; ++m)
#pragma unroll
      for (int n = 0; n < 4; ++n) {
        acc[m][n] = __builtin_amdgcn_mfma_f32_16x16x32_bf16(aH[m], bH[n], acc[m][n], 0, 0, 0);
        acc[m][n] = __builtin_amdgcn_mfma_f32_16x16x32_bf16(aH[m], bL[n], acc[m][n], 0, 0, 0);
        acc[m][n] = __builtin_amdgcn_mfma_f32_16x16x32_bf16(aL[m], bH[n], acc[m][n], 0, 0, 0);
      }
    __syncthreads();
  }

#pragma unroll
  for (int n = 0; n < 4; ++n) {
    float v = -3.0e38f;
#pragma unroll
    for (int m = 0; m < 4; ++m)
#pragma unroll
      for (int j = 0; j < 4; ++j) {
        float rv = ldsR[wr * 64 + m * 16 + fg * 4 + j];
        v = fmaxf(v, acc[m][n][j] * rv);
      }
    v = fmaxf(v, __shfl_xor(v, 16));
    v = fmaxf(v, __shfl_xor(v, 32));
    if (fg == 0) {
      int col = wc * 64 + n * 16 + fr;
      atomicMax(&gmax2[z * CAND + col], encf(v * 0.03125f));
    }
  }
}

// ---------------- K4: final — patch exact vals, top-64, weights, O ----------------
__global__ void final_k(const unsigned* __restrict__ gmax,
                        const unsigned* __restrict__ gmax2,
                        const int* __restrict__ candIdx,
                        const float* __restrict__ alpha_p,
                        const float* __restrict__ E, const float* __restrict__ rinvE,
                        const float* __restrict__ sn_w, const float* __restrict__ on_w,
                        float* __restrict__ wout, float* __restrict__ O) {
  __shared__ unsigned enc[NE];
  __shared__ int sel[NE];
  __shared__ unsigned ubc[4];
  __shared__ float l4[4];
  __shared__ int ic[257];
  int tid = threadIdx.x;
  int lane = tid & 63, w = tid >> 6;
  int b = blockIdx.x;
  const unsigned* g = gmax + (size_t)b * NE;
  for (int i = tid; i < NE; i += 256) enc[i] = g[i];
  __syncthreads();
  if (tid < CAND) enc[candIdx[b * CAND + tid]] = gmax2[b * CAND + tid];  // exact patch
  __syncthreads();

  unsigned mx = 0;
  for (int i = tid; i < NE; i += 256) mx = enc[i] > mx ? enc[i] : mx;
  for (int o = 32; o > 0; o >>= 1) {
    unsigned other = (unsigned)__shfl_xor((int)mx, o);
    if (other > mx) mx = other;
  }
  if (lane == 0) ubc[w] = mx;
  __syncthreads();
  unsigned m1e = ubc[0];
  for (int t = 1; t < 4; ++t) m1e = ubc[t] > m1e ? ubc[t] : m1e;
  float m1 = decf(m1e);

  unsigned cur = 0;
  for (int bit = 31; bit >= 0; --bit) {
    unsigned cand = cur | (1u << bit);
    int c = 0;
    for (int i = tid; i < NE; i += 256) c += (enc[i] >= cand) ? 1 : 0;
    for (int o = 32; o > 0; o >>= 1) c += __shfl_xor(c, o);
    __syncthreads();
    if (lane == 0) ic[w] = c;
    __syncthreads();
    int tot = ic[0] + ic[1] + ic[2] + ic[3];
    if (tot >= KTOP) cur = cand;
    if (tot == KTOP) break;   // set {enc>=cand} is exactly the top-KTOP
  }

  float sd = 0.f, ssum = 0.f;
  for (int i = tid; i < NE; i += 256) {
    float e = expf(decf(enc[i]) - m1);
    sd += e;
    if (enc[i] >= cur) ssum += e;
  }
  for (int o = 32; o > 0; o >>= 1) { sd += __shfl_xor(sd, o); ssum += __shfl_xor(ssum, o); }
  __syncthreads();
  if (lane == 0) { l4[w] = sd; }
  __syncthreads();
  float SD = l4[0] + l4[1] + l4[2] + l4[3];
  __syncthreads();
  if (lane == 0) { l4[w] = ssum; }
  __syncthreads();
  float SS = l4[0] + l4[1] + l4[2] + l4[3];

  float alpha = alpha_p[0];
  float wd = alpha / SD;
  float ws_ = (1.0f - alpha) / SS;
  for (int i = tid; i < NE; i += 256) {
    float e = expf(decf(enc[i]) - m1);
    float wv = wd * e + ((enc[i] >= cur) ? ws_ * e : 0.0f);
    wout[(size_t)b * NE + i] = wv;
  }

  // compact selected indices into LDS
  int myc = 0;
  for (int i = tid; i < NE; i += 256) myc += (enc[i] >= cur) ? 1 : 0;
  __syncthreads();
  ic[tid] = myc;
  __syncthreads();
  if (tid == 0) {
    int s = 0;
    for (int t = 0; t < 256; ++t) { int v = ic[t]; ic[t] = s; s += v; }
    ic[256] = s;
  }
  __syncthreads();
  int off = ic[tid];
  for (int i = tid; i < NE; i += 256)
    if (enc[i] >= cur) sel[off++] = i;
  __syncthreads();
  int nsel = ic[256];

  // O = rmsnorm(weights @ En, on_w)
  float acc[4] = {0.f, 0.f, 0.f, 0.f};
  if (alpha == 0.0f) {
    float coef = wd + ws_;
    for (int j = 0; j < nsel; ++j) {
      int n = sel[j];
      float e = expf(decf(enc[n]) - m1);
      float wv = coef * e * rinvE[n];
      const float* er = E + (size_t)n * D_DIM;
#pragma unroll
      for (int i = 0; i < 4; ++i) acc[i] += wv * er[tid + 256 * i];
    }
  } else {
    for (int n = 0; n < NE; ++n) {
      float e = expf(decf(enc[n]) - m1);
      float wv = (wd * e + ((enc[n] >= cur) ? ws_ * e : 0.0f)) * rinvE[n];
      const float* er = E + (size_t)n * D_DIM;
#pragma unroll
      for (int i = 0; i < 4; ++i) acc[i] += wv * er[tid + 256 * i];
    }
  }
  float ssq = 0.f;
#pragma unroll
  for (int i = 0; i < 4; ++i) {
    acc[i] *= sn_w[tid + 256 * i];
    ssq += acc[i] * acc[i];
  }
  for (int o = 32; o > 0; o >>= 1) ssq += __shfl_xor(ssq, o);
  if (lane == 0) l4[w] = ssq;
  __syncthreads();
  float tot = l4[0] + l4[1] + l4[2] + l4[3];
  float rn = rsqrtf(tot * (1.0f / D_DIM) + 1e-6f);
#pragma unroll
  for (int i = 0; i < 4; ++i)
    O[(size_t)b * D_DIM + tid + 256 * i] = acc[i] * rn * on_w[tid + 256 * i];
}

}  // namespace

extern "C" void kernel_launch(void* const* d_in, const int* in_sizes, int n_in,
                              void* d_out, int out_size, void* d_ws, size_t ws_size,
                              hipStream_t stream) {
  const float* X     = (const float*)d_in[0];
  const float* alpha = (const float*)d_in[1];
  const float* E     = (const float*)d_in[2];
  const float* Wq    = (const float*)d_in[3];
  const float* Wk    = (const float*)d_in[4];
  const float* xn_w  = (const float*)d_in[5];
  const float* sn_w  = (const float*)d_in[6];
  const float* on_w  = (const float*)d_in[7];
  float* O    = (float*)d_out;                          // [16][1024]
  float* Wout = (float*)d_out + (size_t)BATCH * D_DIM;  // [16][4096]

  char* ws = (char*)d_ws;
  size_t off = 0;
  auto alloc = [&](size_t bytes) {
    char* p = ws + off;
    off += (bytes + 255) & ~(size_t)255;
    return p;
  };
  signed char*    XQ    = (signed char*)alloc((size_t)MX * D_DIM);          // 32 MB
  signed char*    PQ    = (signed char*)alloc((size_t)NE * D_DIM);          // 4 MB
  float*          WqTf  = (float*)alloc((size_t)D_DIM * D_DIM * 4);
  unsigned short* WkTH  = (unsigned short*)alloc((size_t)D_DIM * D_DIM * 2);
  unsigned short* WkTL  = (unsigned short*)alloc((size_t)D_DIM * D_DIM * 2);
  unsigned short* W2TH  = (unsigned short*)alloc((size_t)D_DIM * D_DIM * 2);
  unsigned short* W2TL  = (unsigned short*)alloc((size_t)D_DIM * D_DIM * 2);
  unsigned short* PH    = (unsigned short*)alloc((size_t)NE * D_DIM * 2);
  unsigned short* PL    = (unsigned short*)alloc((size_t)NE * D_DIM * 2);
  float*          W2p   = (float*)alloc((size_t)4 * D_DIM * D_DIM * 4);     // 16 MB
  float*          Pp    = (float*)alloc((size_t)2 * NE * D_DIM * 4);        // 32 MB
  float* rinvX = (float*)alloc((size_t)MX * 4);
  float* sxr   = (float*)alloc((size_t)MX * 4);
  float* rinvE = (float*)alloc((size_t)NE * 4);
  float* sp    = (float*)alloc((size_t)NE * 4);
  unsigned* gmax  = (unsigned*)alloc((size_t)BATCH * NE * 4);
  unsigned* gmax2 = (unsigned*)alloc((size_t)BATCH * CAND * 4);
  int* candIdx = (int*)alloc((size_t)BATCH * CAND * 4);
  if (off > ws_size) return;  // needs ~115 MB scratch

  hipMemsetAsync(gmax, 0, (size_t)BATCH * NE * 4, stream);

  row_rinv_k<<<NE, 256, 0, stream>>>(E, rinvE);
  prep_w_k<<<dim3(D_DIM / 32, D_DIM / 32), 256, 0, stream>>>(
      Wq, Wk, sn_w, WqTf, WkTH, WkTL);
  // W2T[j][d] = xn_w[j] * sum_k WqT[j,k] * WkT'[d,k]  — K-split z=4, 256 blocks
  gemm_a32_part_k<256><<<dim3(8, 8, 4), 256, 0, stream>>>(
      WqTf, xn_w, WkTH, WkTL, W2p);
  sum_split_w2_k<<<D_DIM * D_DIM / 1024, 256, 0, stream>>>(
      W2p, W2p + (size_t)D_DIM * D_DIM, W2p + (size_t)2 * D_DIM * D_DIM,
      W2p + (size_t)3 * D_DIM * D_DIM, W2TH, W2TL);
  // P'[n][j] = sum_d (E[n,d]*rinvE[n]) * W2T[j,d]  — K-split z=2, 512 blocks
  gemm_a32_part_k<512><<<dim3(NE / 128, D_DIM / 128, 2), 256, 0, stream>>>(
      E, rinvE, W2TH, W2TL, Pp);
  sum_split_p_k<<<NE, 256, 0, stream>>>(
      Pp, Pp + (size_t)NE * D_DIM, PH, PL, sp, (int*)PQ);

  rinv_quantx_k<<<MX, 256, 0, stream>>>(X, rinvX, sxr, (int*)XQ);
  gemm_scores1_k<<<(MX / 128) * (NE / 256), 512, 0, stream>>>(XQ, PQ, sxr, sp, gmax);

  cand_select_k<<<BATCH, 256, 0, stream>>>(gmax, candIdx, gmax2);
  gemm_rescore_k<<<dim3(SEQ / 128, 1, BATCH), 256, 0, stream>>>(
      X, rinvX, PH, PL, candIdx, gmax2);
  final_k<<<BATCH, 256, 0, stream>>>(gmax, gmax2, candIdx, alpha, E, rinvE,
                                     sn_w, on_w, Wout, O);
}

// Round 18
// 375.261 us; speedup vs baseline: 1.1692x; 1.0165x over previous
//
#include <hip/hip_runtime.h>

// BasisAttention: B=16,S=2048,D=1024,N=4096,K_TOP=64. fp32 in/out.
// R4: approx-then-rescore. R5: scores = Xn@(Km Wq)^T. R8: weight-chain fusion.
// R9/R11: XCD swizzle + L2-fit co-residency. R10: int8 approx pass.
// R11: indirect rescore staging, merged final_k. R16: K-split weight GEMMs.
// R17: 3-buffer one-barrier scores1; early-exit top-k search.
// R18: (a) scores1 K-loop FULLY UNROLLED -> cur/nxt compile-time, ds_read
//      addresses loop-invariant (one vaddr + offset: imm), stage dests
//      constant; kills the rotating-pointer VALU recompute (VALUBusy 24%).
//      (b) gmax memset folded into rinv_quantx_k (one fewer dispatch).

namespace {

constexpr int D_DIM = 1024;
constexpr int NE    = 4096;
constexpr int BATCH = 16;
constexpr int SEQ   = 2048;
constexpr int MX    = BATCH * SEQ;   // 32768
constexpr int KTOP  = 64;
constexpr int CAND  = 128;           // candidates per batch
constexpr int BK    = 32;

using f32x4  = __attribute__((ext_vector_type(4))) float;
using bf16x8 = __attribute__((ext_vector_type(8))) short;
using i32x4  = __attribute__((ext_vector_type(4))) int;

__device__ inline unsigned encf(float f) {
  unsigned u = __float_as_uint(f);
  return (u & 0x80000000u) ? ~u : (u | 0x80000000u);
}
__device__ inline float decf(unsigned e) {
  unsigned u = (e & 0x80000000u) ? (e ^ 0x80000000u) : ~e;
  return __uint_as_float(u);
}

__device__ inline unsigned short f2bf(float f) {  // RNE float->bf16 bits
  unsigned u = __float_as_uint(f);
  unsigned lsb = (u >> 16) & 1u;
  u += 0x7fffu + lsb;
  return (unsigned short)(u >> 16);
}
__device__ inline float bf2f(unsigned short h) {
  return __uint_as_float(((unsigned)h) << 16);
}

__device__ inline void gload16(const void* gsrc, void* ldst) {
  __builtin_amdgcn_global_load_lds(
      (const __attribute__((address_space(1))) unsigned int*)gsrc,
      (__attribute__((address_space(3))) unsigned int*)ldst, 16, 0, 0);
}

// ---------------- K1: per-row rsqrt(mean(x^2)+eps) ----------------
__global__ void row_rinv_k(const float* __restrict__ X, float* __restrict__ rinv) {
  __shared__ float l4[4];
  int row = blockIdx.x;
  float4 v = ((const float4*)(X + (size_t)row * D_DIM))[threadIdx.x];
  float ss = v.x * v.x + v.y * v.y + v.z * v.z + v.w * v.w;
  for (int o = 32; o > 0; o >>= 1) ss += __shfl_xor(ss, o);
  int lane = threadIdx.x & 63, w = threadIdx.x >> 6;
  if (lane == 0) l4[w] = ss;
  __syncthreads();
  if (threadIdx.x == 0) {
    float t = l4[0] + l4[1] + l4[2] + l4[3];
    rinv[row] = rsqrtf(t * (1.0f / D_DIM) + 1e-6f);
  }
}

// ---------------- K1a: fused per-row rinv + int8 quant of X (+ gmax zero) ----------------
__global__ void rinv_quantx_k(const float* __restrict__ X, float* __restrict__ rinv,
                              float* __restrict__ sxr, int* __restrict__ XQ,
                              unsigned* __restrict__ gmax) {
  __shared__ float l4[4], m4[4];
  int row = blockIdx.x;
  if (row < 256) gmax[row * 256 + threadIdx.x] = 0u;   // 64K words total
  float4 v = ((const float4*)(X + (size_t)row * D_DIM))[threadIdx.x];
  float ss = v.x * v.x + v.y * v.y + v.z * v.z + v.w * v.w;
  float am = fmaxf(fmaxf(fabsf(v.x), fabsf(v.y)), fmaxf(fabsf(v.z), fabsf(v.w)));
  for (int o = 32; o > 0; o >>= 1) {
    ss += __shfl_xor(ss, o);
    am = fmaxf(am, __shfl_xor(am, o));
  }
  int lane = threadIdx.x & 63, w = threadIdx.x >> 6;
  if (lane == 0) { l4[w] = ss; m4[w] = am; }
  __syncthreads();
  float t  = l4[0] + l4[1] + l4[2] + l4[3];
  float amax = fmaxf(fmaxf(m4[0], m4[1]), fmaxf(m4[2], m4[3]));
  amax = fmaxf(amax, 1e-30f);
  float ri = rsqrtf(t * (1.0f / D_DIM) + 1e-6f);
  if (threadIdx.x == 0) {
    rinv[row] = ri;
    sxr[row]  = ri * amax * (1.0f / 127.0f);
  }
  float qs = 127.0f / amax;
  int q0 = (int)rintf(v.x * qs) & 0xff;
  int q1 = (int)rintf(v.y * qs) & 0xff;
  int q2 = (int)rintf(v.z * qs) & 0xff;
  int q3 = (int)rintf(v.w * qs) & 0xff;
  XQ[(size_t)row * 256 + threadIdx.x] = q0 | (q1 << 8) | (q2 << 16) | (q3 << 24);
}

// ---------------- K1b: fused Wq fp32-transpose + Wk scaled bf16-split-transpose ----------------
__global__ void prep_w_k(const float* __restrict__ Wq, const float* __restrict__ Wk,
                         const float* __restrict__ cw, float* __restrict__ T,
                         unsigned short* __restrict__ H, unsigned short* __restrict__ L) {
  __shared__ float t[32][33], u[32][33];
  int k0 = blockIdx.x * 32, d0 = blockIdx.y * 32;
  int tx = threadIdx.x & 31, ty4 = (threadIdx.x >> 5) * 4;
#pragma unroll
  for (int i = 0; i < 4; ++i) {
    t[ty4 + i][tx] = Wq[(size_t)(d0 + ty4 + i) * D_DIM + k0 + tx];
    u[ty4 + i][tx] = Wk[(size_t)(d0 + ty4 + i) * D_DIM + k0 + tx];
  }
  __syncthreads();
#pragma unroll
  for (int i = 0; i < 4; ++i) {
    int a = ty4 + i;
    T[(size_t)(k0 + a) * D_DIM + d0 + tx] = t[tx][a];
    float v = u[tx][a] * cw[k0 + a];
    unsigned short h = f2bf(v);
    H[(size_t)(k0 + a) * D_DIM + d0 + tx] = h;
    L[(size_t)(k0 + a) * D_DIM + d0 + tx] = f2bf(v - bf2f(h));
  }
}

// ---------------- K2: PARTIAL O = rowscale(A_f32) @ B(hi,lo)^T over K-slice ----------------
template <int KLEN>
__global__ __launch_bounds__(256, 2) void gemm_a32_part_k(
    const float* __restrict__ A, const float* __restrict__ rinv,
    const unsigned short* __restrict__ BH, const unsigned short* __restrict__ BL,
    float* __restrict__ Of) {
  __shared__ __align__(16) float lA[128 * 32];
  __shared__ __align__(16) unsigned short lBH[128 * 32];
  __shared__ __align__(16) unsigned short lBL[128 * 32];
  __shared__ float ldsR[128];

  int tid = threadIdx.x;
  int lane = tid & 63, wid = tid >> 6;
  int wr = wid >> 1, wc = wid & 1;
  int fr = lane & 15, fg = lane >> 4;
  long m0 = (long)blockIdx.x * 128;
  long n0 = (long)blockIdx.y * 128;
  int kbeg = blockIdx.z * KLEN;
  float* Op = Of + (size_t)blockIdx.z * ((size_t)gridDim.x * 128 * D_DIM);

  if (tid < 128) ldsR[tid] = rinv ? rinv[m0 + tid] : 1.0f;

  f32x4 acc[4][4] = {};

  for (int kk = kbeg; kk < kbeg + KLEN; kk += BK) {
#pragma unroll
    for (int i = 0; i < 4; ++i) {
      int chunk = i * 256 + tid;
      int r = chunk >> 3, c = chunk & 7;
      int cs = c ^ (r & 7);
      const float* src = A + (m0 + r) * (long)D_DIM + kk + cs * 4;
      gload16(src, (void*)(lA + ((i * 256 + (tid & ~63)) << 2)));
    }
#pragma unroll
    for (int i = 0; i < 2; ++i) {
      int chunk = i * 256 + tid;
      int r = chunk >> 2, c = chunk & 3;
      int cs = c ^ ((r >> 1) & 3);
      long boff = (n0 + r) * (long)D_DIM + kk + cs * 8;
      int lo = (i * 256 + (tid & ~63)) << 3;
      gload16(BH + boff, (void*)(lBH + lo));
      gload16(BL + boff, (void*)(lBL + lo));
    }
    __syncthreads();

    bf16x8 aH[4], aL[4], bH[4], bL[4];
#pragma unroll
    for (int m = 0; m < 4; ++m) {
      int row = wr * 64 + m * 16 + fr;
      int rm = row & 7;
      f32x4 p0 = *(const f32x4*)(lA + row * 32 + (((fg * 2 + 0) ^ rm) * 4));
      f32x4 p1 = *(const f32x4*)(lA + row * 32 + (((fg * 2 + 1) ^ rm) * 4));
#pragma unroll
      for (int e = 0; e < 8; ++e) {
        float f = (e < 4) ? p0[e] : p1[e - 4];
        unsigned short h = f2bf(f);
        aH[m][e] = (short)h;
        aL[m][e] = (short)f2bf(f - bf2f(h));
      }
    }
#pragma unroll
    for (int n = 0; n < 4; ++n) {
      int row = wc * 64 + n * 16 + fr;
      int sc = fg ^ ((row >> 1) & 3);
      bH[n] = *(const bf16x8*)(lBH + row * 32 + sc * 8);
      bL[n] = *(const bf16x8*)(lBL + row * 32 + sc * 8);
    }
#pragma unroll
    for (int m = 0; m < 4; ++m)
#pragma unroll
      for (int n = 0; n < 4; ++n) {
        acc[m][n] = __builtin_amdgcn_mfma_f32_16x16x32_bf16(aH[m], bH[n], acc[m][n], 0, 0, 0);
        acc[m][n] = __builtin_amdgcn_mfma_f32_16x16x32_bf16(aH[m], bL[n], acc[m][n], 0, 0, 0);
        acc[m][n] = __builtin_amdgcn_mfma_f32_16x16x32_bf16(aL[m], bH[n], acc[m][n], 0, 0, 0);
      }
    __syncthreads();
  }

#pragma unroll
  for (int m = 0; m < 4; ++m) {
#pragma unroll
    for (int j = 0; j < 4; ++j) {
      int rloc = wr * 64 + m * 16 + fg * 4 + j;
      float rv = ldsR[rloc];
      long grow = m0 + rloc;
#pragma unroll
      for (int n = 0; n < 4; ++n) {
        long gcol = n0 + wc * 64 + n * 16 + fr;
        Op[grow * D_DIM + gcol] = acc[m][n][j] * rv;
      }
    }
  }
}

// ---------------- K2b: sum 4 partials -> bf16 hi/lo split (W2T) ----------------
__global__ void sum_split_w2_k(const float* __restrict__ P0, const float* __restrict__ P1,
                               const float* __restrict__ P2, const float* __restrict__ P3,
                               unsigned short* __restrict__ H, unsigned short* __restrict__ L) {
  size_t i4 = ((size_t)blockIdx.x * 256 + threadIdx.x) * 4;
  float4 a = *(const float4*)(P0 + i4);
  float4 b = *(const float4*)(P1 + i4);
  float4 c = *(const float4*)(P2 + i4);
  float4 d = *(const float4*)(P3 + i4);
  float v[4] = {a.x + b.x + c.x + d.x, a.y + b.y + c.y + d.y,
                a.z + b.z + c.z + d.z, a.w + b.w + c.w + d.w};
  unsigned short h[4], l[4];
#pragma unroll
  for (int i = 0; i < 4; ++i) {
    h[i] = f2bf(v[i]);
    l[i] = f2bf(v[i] - bf2f(h[i]));
  }
  *(ushort4*)(H + i4) = make_ushort4(h[0], h[1], h[2], h[3]);
  *(ushort4*)(L + i4) = make_ushort4(l[0], l[1], l[2], l[3]);
}

// ---------------- K2c: sum 2 partials -> PH/PL split + row amax + int8 PQ ----------------
__global__ void sum_split_p_k(const float* __restrict__ P0, const float* __restrict__ P1,
                              unsigned short* __restrict__ PH, unsigned short* __restrict__ PL,
                              float* __restrict__ sp, int* __restrict__ PQ) {
  __shared__ float m4[4];
  int row = blockIdx.x, tid = threadIdx.x;
  size_t i4 = (size_t)row * D_DIM + tid * 4;
  float4 a = *(const float4*)(P0 + i4);
  float4 b = *(const float4*)(P1 + i4);
  float v0 = a.x + b.x, v1 = a.y + b.y, v2 = a.z + b.z, v3 = a.w + b.w;
  unsigned short h0 = f2bf(v0), h1 = f2bf(v1), h2 = f2bf(v2), h3 = f2bf(v3);
  *(ushort4*)(PH + i4) = make_ushort4(h0, h1, h2, h3);
  *(ushort4*)(PL + i4) = make_ushort4(f2bf(v0 - bf2f(h0)), f2bf(v1 - bf2f(h1)),
                                      f2bf(v2 - bf2f(h2)), f2bf(v3 - bf2f(h3)));
  float am = fmaxf(fmaxf(fabsf(v0), fabsf(v1)), fmaxf(fabsf(v2), fabsf(v3)));
  for (int o = 32; o > 0; o >>= 1) am = fmaxf(am, __shfl_xor(am, o));
  int lane = tid & 63, w = tid >> 6;
  if (lane == 0) m4[w] = am;
  __syncthreads();
  float amax = fmaxf(fmaxf(m4[0], m4[1]), fmaxf(m4[2], m4[3]));
  amax = fmaxf(amax, 1e-30f);
  if (tid == 0) sp[row] = amax * (1.0f / 127.0f);
  float qs = 127.0f / amax;
  int q0 = (int)rintf(v0 * qs) & 0xff;
  int q1 = (int)rintf(v1 * qs) & 0xff;
  int q2 = (int)rintf(v2 * qs) & 0xff;
  int q3 = (int)rintf(v3 * qs) & 0xff;
  PQ[(size_t)row * 256 + tid] = q0 | (q1 << 8) | (q2 << 16) | (q3 << 24);
}

// ---------------- K3a: APPROX scores INT8 — 128x256 tile, 8 waves (2m x 4n),
// 3 LDS buffers, ONE barrier per K-tile, FULLY UNROLLED K-loop ----------------
__global__ __launch_bounds__(512, 4) void gemm_scores1_k(
    const signed char* __restrict__ XQ, const signed char* __restrict__ PQ,
    const float* __restrict__ sxr, const float* __restrict__ sp,
    unsigned* __restrict__ gmax) {
  __shared__ __align__(16) signed char lA[3][128 * 64];   // 24 KB
  __shared__ __align__(16) signed char lB[3][256 * 64];   // 48 KB
  __shared__ float ldsR[128];

  int tid = threadIdx.x;                 // 0..511
  int lane = tid & 63, wid = tid >> 6;   // 8 waves
  int wwr = wid >> 2;                    // 0..1  (m half: 64 rows each)
  int wwc = wid & 3;                     // 0..3  (n quarter: 64 cols each)
  int fr = lane & 15, fg = lane >> 4;

  int id = blockIdx.x;                   // 0..4095
  int xcd = id & 7;
  int r = id >> 3;                       // 0..511
  int tile_n = (r & 7) | ((r >> 8) << 3);      // 0..15
  int tile_m = xcd * 32 + ((r >> 3) & 31);     // 0..255
  long m0 = (long)tile_m * 128;
  long n0 = (long)tile_n * 256;

  if (tid < 128) ldsR[tid] = sxr[m0 + tid];

  // stage: A 8KB (512 x 16B chunks, 1/thread), B 16KB (1024 chunks, 2/thread)
  auto stageTile = [&](int buf, int kt) {
    int kk = kt * 64;
    {
      int r2 = tid >> 2, c = tid & 3;
      int cs = c ^ ((r2 >> 1) & 3);            // pre-swizzled source
      gload16(XQ + (m0 + r2) * (long)D_DIM + kk + cs * 16,
              (void*)(&lA[buf][0] + ((tid & ~63) << 4)));
    }
#pragma unroll
    for (int i = 0; i < 2; ++i) {
      int chunk = i * 512 + tid;
      int r2 = chunk >> 2, c = chunk & 3;
      int cs = c ^ ((r2 >> 1) & 3);
      gload16(PQ + (n0 + r2) * (long)D_DIM + kk + cs * 16,
              (void*)(&lB[buf][0] + ((i * 512 + (tid & ~63)) << 4)));
    }
  };

  i32x4 acc[4][4] = {};

  stageTile(0, 0);
  stageTile(1, 1);
  asm volatile("s_waitcnt lgkmcnt(0)" ::: "memory");  // ldsR visible at barrier

#pragma unroll
  for (int kt = 0; kt < 16; ++kt) {
    const int cur = kt % 3;                 // compile-time after unroll
    const int nxt = (kt + 2) % 3;
    const signed char* As = &lA[cur][0];
    const signed char* Bs = &lB[cur][0];

    if (kt < 15) {
      asm volatile("s_waitcnt vmcnt(3)" ::: "memory");
    } else {
      asm volatile("s_waitcnt vmcnt(0)" ::: "memory");
    }
    __builtin_amdgcn_s_barrier();
    // single barrier: all waves' kt-1 reads retired (consumed by MFMAs),
    // so buf[nxt] (== buf[(kt-1)%3]) is safe to overwrite now.
    if (kt + 2 < 16) stageTile(nxt, kt + 2);

    i32x4 aF[4], bF[4];
#pragma unroll
    for (int mi = 0; mi < 4; ++mi) {
      int row = wwr * 64 + mi * 16 + fr;
      int ck = fg ^ ((row >> 1) & 3);
      aF[mi] = *(const i32x4*)(As + row * 64 + ck * 16);
    }
#pragma unroll
    for (int ni = 0; ni < 4; ++ni) {
      int row = wwc * 64 + ni * 16 + fr;
      int ck = fg ^ ((row >> 1) & 3);
      bF[ni] = *(const i32x4*)(Bs + row * 64 + ck * 16);
    }
    __builtin_amdgcn_s_setprio(1);
#pragma unroll
    for (int mi = 0; mi < 4; ++mi)
#pragma unroll
      for (int ni = 0; ni < 4; ++ni)
        acc[mi][ni] = __builtin_amdgcn_mfma_i32_16x16x64_i8(
            aF[mi], bF[ni], acc[mi][ni], 0, 0, 0);
    __builtin_amdgcn_s_setprio(0);
  }

  // epilogue: v = acc*sxr[row]*sp[col]; per-wave column max over 64 rows.
  int b = (int)(m0 >> 11);
#pragma unroll
  for (int ni = 0; ni < 4; ++ni) {
    long col = n0 + wwc * 64 + ni * 16 + fr;
    float spc = sp[col];
    float v = -3.0e38f;
#pragma unroll
    for (int mi = 0; mi < 4; ++mi)
#pragma unroll
      for (int j = 0; j < 4; ++j) {
        int row = wwr * 64 + mi * 16 + fg * 4 + j;
        v = fmaxf(v, (float)acc[mi][ni][j] * ldsR[row]);
      }
    v *= spc;
    v = fmaxf(v, __shfl_xor(v, 16));
    v = fmaxf(v, __shfl_xor(v, 32));
    if (fg == 0) {
      atomicMax(&gmax[(long)b * NE + col], encf(v * 0.03125f));
    }
  }
}

// ---------------- K3b: per-batch top-CAND candidate selection (+ zero gmax2) ----------------
__global__ void cand_select_k(const unsigned* __restrict__ gmax,
                              int* __restrict__ candIdx, unsigned* __restrict__ gmax2) {
  __shared__ unsigned enc[NE];
  __shared__ int ic[257];
  int tid = threadIdx.x;
  int lane = tid & 63, w = tid >> 6;
  int zb = blockIdx.x;
  if (tid < CAND) gmax2[zb * CAND + tid] = 0u;
  const unsigned* g = gmax + (size_t)zb * NE;
  for (int i = tid; i < NE; i += 256) enc[i] = g[i];
  __syncthreads();

  unsigned cur = 0;
  for (int bit = 31; bit >= 0; --bit) {
    unsigned cand = cur | (1u << bit);
    int c = 0;
    for (int i = tid; i < NE; i += 256) c += (enc[i] >= cand) ? 1 : 0;
    for (int o = 32; o > 0; o >>= 1) c += __shfl_xor(c, o);
    __syncthreads();
    if (lane == 0) ic[w] = c;
    __syncthreads();
    int tot = ic[0] + ic[1] + ic[2] + ic[3];
    if (tot >= CAND) cur = cand;
    if (tot == CAND) break;   // set {enc>=cand} is exactly the top-CAND
  }

  int myc = 0;
  for (int i = tid; i < NE; i += 256) myc += (enc[i] >= cur) ? 1 : 0;
  __syncthreads();
  ic[tid] = myc;
  __syncthreads();
  if (tid == 0) {
    int s = 0;
    for (int t = 0; t < 256; ++t) { int v = ic[t]; ic[t] = s; s += v; }
  }
  __syncthreads();
  int off = ic[tid];
  for (int i = tid; i < NE; i += 256)
    if (enc[i] >= cur) {
      if (off < CAND) candIdx[zb * CAND + off] = i;
      ++off;
    }
}

// ---------------- K3d: EXACT rescore (indirect candidate staging) ----------------
__global__ __launch_bounds__(256, 2) void gemm_rescore_k(
    const float* __restrict__ X, const float* __restrict__ rinvA,
    const unsigned short* __restrict__ PH, const unsigned short* __restrict__ PL,
    const int* __restrict__ candIdx, unsigned* __restrict__ gmax2) {
  __shared__ __align__(16) float lA[128 * 32];
  __shared__ __align__(16) unsigned short lBH[128 * 32], lBL[128 * 32];
  __shared__ float ldsR[128];

  int tid = threadIdx.x;
  int lane = tid & 63, wid = tid >> 6;
  int wr = wid >> 1, wc = wid & 1;
  int fr = lane & 15, fg = lane >> 4;
  int z = blockIdx.z;
  long m0 = (long)blockIdx.x * 128;
  long arow0 = (long)z * SEQ + m0;

  if (tid < 128) ldsR[tid] = rinvA[arow0 + tid];

  long bbase[2];
#pragma unroll
  for (int i = 0; i < 2; ++i) {
    int r = (i * 256 + tid) >> 2;          // 0..127
    bbase[i] = (long)candIdx[z * CAND + r] * D_DIM;
  }

  f32x4 acc[4][4] = {};

  for (int kk = 0; kk < D_DIM; kk += BK) {
#pragma unroll
    for (int i = 0; i < 4; ++i) {
      int chunk = i * 256 + tid;
      int r = chunk >> 3, c = chunk & 7;
      int cs = c ^ (r & 7);
      const float* src = X + (arow0 + r) * (long)D_DIM + kk + cs * 4;
      gload16(src, (void*)(lA + ((i * 256 + (tid & ~63)) << 2)));
    }
#pragma unroll
    for (int i = 0; i < 2; ++i) {
      int chunk = i * 256 + tid;
      int c = chunk & 3;
      int r = chunk >> 2;
      int cs = c ^ ((r >> 1) & 3);
      long boff = bbase[i] + kk + cs * 8;
      int lo = (i * 256 + (tid & ~63)) << 3;
      gload16(PH + boff, (void*)(lBH + lo));
      gload16(PL + boff, (void*)(lBL + lo));
    }
    __syncthreads();

    bf16x8 aH[4], aL[4], bH[4], bL[4];
#pragma unroll
    for (int m = 0; m < 4; ++m) {
      int row = wr * 64 + m * 16 + fr;
      int rm = row & 7;
      f32x4 p0 = *(const f32x4*)(lA + row * 32 + (((fg * 2 + 0) ^ rm) * 4));
      f32x4 p1 = *(const f32x4*)(lA + row * 32 + (((fg * 2 + 1) ^ rm) * 4));
#pragma unroll
      for (int e = 0; e < 8; ++e) {
        float f = (e < 4) ? p0[e] : p1[e - 4];
        unsigned short h = f2bf(f);
        aH[m][e] = (short)h;
        aL[m][e] = (short)f2bf(f - bf2f(h));
      }
    }
#pragma unroll
    for (int n = 0; n < 4; ++n) {
      int row = wc * 64 + n * 16 + fr;
      int sc = fg ^ ((row >> 1) & 3);
      bH[n] = *(const bf16x8*)(lBH + row * 32 + sc * 8);
      bL[n] = *(const bf16x8*)(lBL + row * 32 + sc * 8);
    }
#pragma unroll
    for (int m = 0; m < 4; ++m)
#pragma unroll
      for (int n = 0; n < 4; ++n) {
        acc[m][n] = __builtin_amdgcn_mfma_f32_16x16x32_bf16(aH[m], bH[n], acc[m][n], 0, 0, 0);
        acc[m][n] = __builtin_amdgcn_mfma_f32_16x16x32_bf16(aH[m], bL[n], acc[m][n], 0, 0, 0);
        acc[m][n] = __builtin_amdgcn_mfma_f32_16x16x32_bf16(aL[m], bH[n], acc[m][n], 0, 0, 0);
      }
    __syncthreads();
  }

#pragma unroll
  for (int n = 0; n < 4; ++n) {
    float v = -3.0e38f;
#pragma unroll
    for (int m = 0; m < 4; ++m)
#pragma unroll
      for (int j = 0; j < 4; ++j) {
        float rv = ldsR[wr * 64 + m * 16 + fg * 4 + j];
        v = fmaxf(v, acc[m][n][j] * rv);
      }
    v = fmaxf(v, __shfl_xor(v, 16));
    v = fmaxf(v, __shfl_xor(v, 32));
    if (fg == 0) {
      int col = wc * 64 + n * 16 + fr;
      atomicMax(&gmax2[z * CAND + col], encf(v * 0.03125f));
    }
  }
}

// ---------------- K4: final — patch exact vals, top-64, weights, O ----------------
__global__ void final_k(const unsigned* __restrict__ gmax,
                        const unsigned* __restrict__ gmax2,
                        const int* __restrict__ candIdx,
                        const float* __restrict__ alpha_p,
                        const float* __restrict__ E, const float* __restrict__ rinvE,
                        const float* __restrict__ sn_w, const float* __restrict__ on_w,
                        float* __restrict__ wout, float* __restrict__ O) {
  __shared__ unsigned enc[NE];
  __shared__ int sel[NE];
  __shared__ unsigned ubc[4];
  __shared__ float l4[4];
  __shared__ int ic[257];
  int tid = threadIdx.x;
  int lane = tid & 63, w = tid >> 6;
  int b = blockIdx.x;
  const unsigned* g = gmax + (size_t)b * NE;
  for (int i = tid; i < NE; i += 256) enc[i] = g[i];
  __syncthreads();
  if (tid < CAND) enc[candIdx[b * CAND + tid]] = gmax2[b * CAND + tid];  // exact patch
  __syncthreads();

  unsigned mx = 0;
  for (int i = tid; i < NE; i += 256) mx = enc[i] > mx ? enc[i] : mx;
  for (int o = 32; o > 0; o >>= 1) {
    unsigned other = (unsigned)__shfl_xor((int)mx, o);
    if (other > mx) mx = other;
  }
  if (lane == 0) ubc[w] = mx;
  __syncthreads();
  unsigned m1e = ubc[0];
  for (int t = 1; t < 4; ++t) m1e = ubc[t] > m1e ? ubc[t] : m1e;
  float m1 = decf(m1e);

  unsigned cur = 0;
  for (int bit = 31; bit >= 0; --bit) {
    unsigned cand = cur | (1u << bit);
    int c = 0;
    for (int i = tid; i < NE; i += 256) c += (enc[i] >= cand) ? 1 : 0;
    for (int o = 32; o > 0; o >>= 1) c += __shfl_xor(c, o);
    __syncthreads();
    if (lane == 0) ic[w] = c;
    __syncthreads();
    int tot = ic[0] + ic[1] + ic[2] + ic[3];
    if (tot >= KTOP) cur = cand;
    if (tot == KTOP) break;   // set {enc>=cand} is exactly the top-KTOP
  }

  float sd = 0.f, ssum = 0.f;
  for (int i = tid; i < NE; i += 256) {
    float e = expf(decf(enc[i]) - m1);
    sd += e;
    if (enc[i] >= cur) ssum += e;
  }
  for (int o = 32; o > 0; o >>= 1) { sd += __shfl_xor(sd, o); ssum += __shfl_xor(ssum, o); }
  __syncthreads();
  if (lane == 0) { l4[w] = sd; }
  __syncthreads();
  float SD = l4[0] + l4[1] + l4[2] + l4[3];
  __syncthreads();
  if (lane == 0) { l4[w] = ssum; }
  __syncthreads();
  float SS = l4[0] + l4[1] + l4[2] + l4[3];

  float alpha = alpha_p[0];
  float wd = alpha / SD;
  float ws_ = (1.0f - alpha) / SS;
  for (int i = tid; i < NE; i += 256) {
    float e = expf(decf(enc[i]) - m1);
    float wv = wd * e + ((enc[i] >= cur) ? ws_ * e : 0.0f);
    wout[(size_t)b * NE + i] = wv;
  }

  // compact selected indices into LDS
  int myc = 0;
  for (int i = tid; i < NE; i += 256) myc += (enc[i] >= cur) ? 1 : 0;
  __syncthreads();
  ic[tid] = myc;
  __syncthreads();
  if (tid == 0) {
    int s = 0;
    for (int t = 0; t < 256; ++t) { int v = ic[t]; ic[t] = s; s += v; }
    ic[256] = s;
  }
  __syncthreads();
  int off = ic[tid];
  for (int i = tid; i < NE; i += 256)
    if (enc[i] >= cur) sel[off++] = i;
  __syncthreads();
  int nsel = ic[256];

  // O = rmsnorm(weights @ En, on_w)
  float acc[4] = {0.f, 0.f, 0.f, 0.f};
  if (alpha == 0.0f) {
    float coef = wd + ws_;
    for (int j = 0; j < nsel; ++j) {
      int n = sel[j];
      float e = expf(decf(enc[n]) - m1);
      float wv = coef * e * rinvE[n];
      const float* er = E + (size_t)n * D_DIM;
#pragma unroll
      for (int i = 0; i < 4; ++i) acc[i] += wv * er[tid + 256 * i];
    }
  } else {
    for (int n = 0; n < NE; ++n) {
      float e = expf(decf(enc[n]) - m1);
      float wv = (wd * e + ((enc[n] >= cur) ? ws_ * e : 0.0f)) * rinvE[n];
      const float* er = E + (size_t)n * D_DIM;
#pragma unroll
      for (int i = 0; i < 4; ++i) acc[i] += wv * er[tid + 256 * i];
    }
  }
  float ssq = 0.f;
#pragma unroll
  for (int i = 0; i < 4; ++i) {
    acc[i] *= sn_w[tid + 256 * i];
    ssq += acc[i] * acc[i];
  }
  for (int o = 32; o > 0; o >>= 1) ssq += __shfl_xor(ssq, o);
  if (lane == 0) l4[w] = ssq;
  __syncthreads();
  float tot = l4[0] + l4[1] + l4[2] + l4[3];
  float rn = rsqrtf(tot * (1.0f / D_DIM) + 1e-6f);
#pragma unroll
  for (int i = 0; i < 4; ++i)
    O[(size_t)b * D_DIM + tid + 256 * i] = acc[i] * rn * on_w[tid + 256 * i];
}

}  // namespace

extern "C" void kernel_launch(void* const* d_in, const int* in_sizes, int n_in,
                              void* d_out, int out_size, void* d_ws, size_t ws_size,
                              hipStream_t stream) {
  const float* X     = (const float*)d_in[0];
  const float* alpha = (const float*)d_in[1];
  const float* E     = (const float*)d_in[2];
  const float* Wq    = (const float*)d_in[3];
  const float* Wk    = (const float*)d_in[4];
  const float* xn_w  = (const float*)d_in[5];
  const float* sn_w  = (const float*)d_in[6];
  const float* on_w  = (const float*)d_in[7];
  float* O    = (float*)d_out;                          // [16][1024]
  float* Wout = (float*)d_out + (size_t)BATCH * D_DIM;  // [16][4096]

  char* ws = (char*)d_ws;
  size_t off = 0;
  auto alloc = [&](size_t bytes) {
    char* p = ws + off;
    off += (bytes + 255) & ~(size_t)255;
    return p;
  };
  signed char*    XQ    = (signed char*)alloc((size_t)MX * D_DIM);          // 32 MB
  signed char*    PQ    = (signed char*)alloc((size_t)NE * D_DIM);          // 4 MB
  float*          WqTf  = (float*)alloc((size_t)D_DIM * D_DIM * 4);
  unsigned short* WkTH  = (unsigned short*)alloc((size_t)D_DIM * D_DIM * 2);
  unsigned short* WkTL  = (unsigned short*)alloc((size_t)D_DIM * D_DIM * 2);
  unsigned short* W2TH  = (unsigned short*)alloc((size_t)D_DIM * D_DIM * 2);
  unsigned short* W2TL  = (unsigned short*)alloc((size_t)D_DIM * D_DIM * 2);
  unsigned short* PH    = (unsigned short*)alloc((size_t)NE * D_DIM * 2);
  unsigned short* PL    = (unsigned short*)alloc((size_t)NE * D_DIM * 2);
  float*          W2p   = (float*)alloc((size_t)4 * D_DIM * D_DIM * 4);     // 16 MB
  float*          Pp    = (float*)alloc((size_t)2 * NE * D_DIM * 4);        // 32 MB
  float* rinvX = (float*)alloc((size_t)MX * 4);
  float* sxr   = (float*)alloc((size_t)MX * 4);
  float* rinvE = (float*)alloc((size_t)NE * 4);
  float* sp    = (float*)alloc((size_t)NE * 4);
  unsigned* gmax  = (unsigned*)alloc((size_t)BATCH * NE * 4);
  unsigned* gmax2 = (unsigned*)alloc((size_t)BATCH * CAND * 4);
  int* candIdx = (int*)alloc((size_t)BATCH * CAND * 4);
  if (off > ws_size) return;  // needs ~115 MB scratch

  row_rinv_k<<<NE, 256, 0, stream>>>(E, rinvE);
  prep_w_k<<<dim3(D_DIM / 32, D_DIM / 32), 256, 0, stream>>>(
      Wq, Wk, sn_w, WqTf, WkTH, WkTL);
  // W2T[j][d] = xn_w[j] * sum_k WqT[j,k] * WkT'[d,k]  — K-split z=4, 256 blocks
  gemm_a32_part_k<256><<<dim3(8, 8, 4), 256, 0, stream>>>(
      WqTf, xn_w, WkTH, WkTL, W2p);
  sum_split_w2_k<<<D_DIM * D_DIM / 1024, 256, 0, stream>>>(
      W2p, W2p + (size_t)D_DIM * D_DIM, W2p + (size_t)2 * D_DIM * D_DIM,
      W2p + (size_t)3 * D_DIM * D_DIM, W2TH, W2TL);
  // P'[n][j] = sum_d (E[n,d]*rinvE[n]) * W2T[j,d]  — K-split z=2, 512 blocks
  gemm_a32_part_k<512><<<dim3(NE / 128, D_DIM / 128, 2), 256, 0, stream>>>(
      E, rinvE, W2TH, W2TL, Pp);
  sum_split_p_k<<<NE, 256, 0, stream>>>(
      Pp, Pp + (size_t)NE * D_DIM, PH, PL, sp, (int*)PQ);

  rinv_quantx_k<<<MX, 256, 0, stream>>>(X, rinvX, sxr, (int*)XQ, gmax);
  gemm_scores1_k<<<(MX / 128) * (NE / 256), 512, 0, stream>>>(XQ, PQ, sxr, sp, gmax);

  cand_select_k<<<BATCH, 256, 0, stream>>>(gmax, candIdx, gmax2);
  gemm_rescore_k<<<dim3(SEQ / 128, 1, BATCH), 256, 0, stream>>>(
      X, rinvX, PH, PL, candIdx, gmax2);
  final_k<<<BATCH, 256, 0, stream>>>(gmax, gmax2, candIdx, alpha, E, rinvE,
                                     sn_w, on_w, Wout, O);
}